// Round 3
// baseline (402.751 us; speedup 1.0000x reference)
//
#include <hip/hip_runtime.h>
#include <hip/hip_bf16.h>
#include <stdint.h>

// Problem: b=32, s=256, h=1024, 5 options.
// out = 0.5 * sum_n V_n @ o_n,  V_n = sum_{i!=n} softmax_k(q_i . o_k)_n,  q_i = o_i @ W
// bias is softmax-shift-invariant -> ignored.
// Round 3: ws_size < 275MB caused silent early-return (absmax identical to stub).
// Scratch cut to 107MB: Wt(2MB) + Qb(84MB) + Vb(21MB). fp32 inputs are cast
// in-staging; pvgemm transposes o_n in LDS. Canary reports ws_size if still short.

#define BB 32
#define SS 256
#define HH 1024

typedef __attribute__((ext_vector_type(4))) float f32x4;
typedef __attribute__((ext_vector_type(8))) __bf16 bf16x8;
typedef __attribute__((ext_vector_type(4))) __bf16 bf16x4;

__device__ constexpr int PAIR(int i, int n) { return i * 4 + (n > i ? n - 1 : n); }

__global__ void canary(float* out, float v) { out[0] = v; }

// ---------------------------------------------------------------------------
// W (1024x1024 fp32) -> Wt (bf16, transposed). 64x64 tiles, grid 256.
__global__ __launch_bounds__(256) void cast_trW(const float* __restrict__ src,
                                                __bf16* __restrict__ dstT)
{
  __shared__ __bf16 tile[64][72];
  int ct = blockIdx.x & 15, rt = blockIdx.x >> 4;
  const float* s = src + (long)(rt * 64) * 1024 + ct * 64;
  int t = threadIdx.x;
#pragma unroll
  for (int p = 0; p < 4; p++) {
    int c = t + p * 256;
    int row = c >> 4, c4 = c & 15;
    float4 v = *(const float4*)(s + (long)row * 1024 + c4 * 4);
    bf16x4 h;
    h[0] = (__bf16)v.x; h[1] = (__bf16)v.y; h[2] = (__bf16)v.z; h[3] = (__bf16)v.w;
    *(bf16x4*)&tile[row][c4 * 4] = h;
  }
  __syncthreads();
#pragma unroll
  for (int p = 0; p < 4; p++) {
    int c = t + p * 256;
    int hr = c >> 4, s4 = c & 15;
    bf16x4 h;
    h[0] = tile[s4 * 4 + 0][hr];
    h[1] = tile[s4 * 4 + 1][hr];
    h[2] = tile[s4 * 4 + 2][hr];
    h[3] = tile[s4 * 4 + 3][hr];
    *(bf16x4*)(dstT + (long)(ct * 64 + hr) * 1024 + rt * 64 + s4 * 4) = h;
  }
}

// ---------------------------------------------------------------------------
// Q = o @ W. A: fp32 option rows (cast in staging). B: Wt bf16 (k-contig rows).
// 128x128 tile, BK=32, 4 waves (2x2), 4x4 of 16x16x32 MFMA per wave.
__global__ __launch_bounds__(256) void qgemm(
    const float* p0, const float* p1, const float* p2, const float* p3, const float* p4,
    const __bf16* __restrict__ Bt, __bf16* __restrict__ C)
{
  __shared__ __bf16 smA[128][40];
  __shared__ __bf16 smB[128][40];
  int rt = blockIdx.x, ct = blockIdx.y;
  int m = rt >> 6;  // option index (block-uniform)
  const float* A32 = m == 0 ? p0 : m == 1 ? p1 : m == 2 ? p2 : m == 3 ? p3 : p4;
  long rbase = (long)(rt & 63) * 128;
  int t = threadIdx.x, l = t & 63, w = t >> 6;
  int wm = w >> 1, wn = w & 1;
  f32x4 acc[4][4] = {};
  for (int k0 = 0; k0 < 1024; k0 += 32) {
    {  // A: 128 rows x 32 k fp32 -> bf16
      int row = t >> 1, half = (t & 1) * 16;
      const float* src = A32 + (rbase + row) * 1024 + k0 + half;
      float4 v0 = *(const float4*)(src);
      float4 v1 = *(const float4*)(src + 4);
      float4 v2 = *(const float4*)(src + 8);
      float4 v3 = *(const float4*)(src + 12);
      bf16x8 h0, h1;
      h0[0] = (__bf16)v0.x; h0[1] = (__bf16)v0.y; h0[2] = (__bf16)v0.z; h0[3] = (__bf16)v0.w;
      h0[4] = (__bf16)v1.x; h0[5] = (__bf16)v1.y; h0[6] = (__bf16)v1.z; h0[7] = (__bf16)v1.w;
      h1[0] = (__bf16)v2.x; h1[1] = (__bf16)v2.y; h1[2] = (__bf16)v2.z; h1[3] = (__bf16)v2.w;
      h1[4] = (__bf16)v3.x; h1[5] = (__bf16)v3.y; h1[6] = (__bf16)v3.z; h1[7] = (__bf16)v3.w;
      *(bf16x8*)&smA[row][half] = h0;
      *(bf16x8*)&smA[row][half + 8] = h1;
    }
#pragma unroll
    for (int p = 0; p < 2; p++) {  // B: Wt rows (bf16, coalesced)
      int c = t + p * 256;
      int row = c >> 2, sl = c & 3;
      *(bf16x8*)&smB[row][sl * 8] =
          *(const bf16x8*)(Bt + (long)(ct * 128 + row) * 1024 + k0 + sl * 8);
    }
    __syncthreads();
    bf16x8 af[4], bfr[4];
    int sl = l >> 4, lr = l & 15;
#pragma unroll
    for (int i = 0; i < 4; i++) {
      af[i]  = *(const bf16x8*)&smA[wm * 64 + i * 16 + lr][sl * 8];
      bfr[i] = *(const bf16x8*)&smB[wn * 64 + i * 16 + lr][sl * 8];
    }
#pragma unroll
    for (int i = 0; i < 4; i++)
#pragma unroll
      for (int j = 0; j < 4; j++)
        acc[i][j] = __builtin_amdgcn_mfma_f32_16x16x32_bf16(af[i], bfr[j], acc[i][j], 0, 0, 0);
    __syncthreads();
  }
#pragma unroll
  for (int i = 0; i < 4; i++) {
    long mrow = (long)rt * 128 + wm * 64 + i * 16 + ((l >> 4) << 2);
#pragma unroll
    for (int j = 0; j < 4; j++) {
      int n = ct * 128 + wn * 64 + j * 16 + (l & 15);
#pragma unroll
      for (int r = 0; r < 4; r++)
        C[(mrow + r) * 1024 + n] = (__bf16)acc[i][j][r];
    }
  }
}

// ---------------------------------------------------------------------------
// All 20 cross-grams + lane-local softmax over 4 options -> combined weights V.
// Block: 512 thr (8 waves, 2x4 patches of 16x16) covers 32 s1 x 64 s2.
__global__ __launch_bounds__(512) void gram_softmax(
    const __bf16* __restrict__ Q,
    const float* p0, const float* p1, const float* p2, const float* p3, const float* p4,
    __bf16* __restrict__ V)
{
  __shared__ __bf16 sq[5][32][40];  // 12.8 KB
  __shared__ __bf16 so[5][64][40];  // 25.6 KB
  int bid = blockIdx.x;
  int b = bid >> 5, s1t = (bid >> 2) & 7, s2t = bid & 3;
  int t = threadIdx.x, l = t & 63, w = t >> 6;
  int pr = w >> 2, pc = w & 3;
  f32x4 acc[20] = {};
  for (int k0 = 0; k0 < 1024; k0 += 32) {
    for (int c = t; c < 640; c += 512) {  // Q tiles: 5 x 32 rows x 4 slots (bf16)
      int m = c >> 7, r = (c >> 2) & 31, sl = c & 3;
      *(bf16x8*)&sq[m][r][sl * 8] =
          *(const bf16x8*)(Q + ((long)(m * 32 + b) * 256 + s1t * 32 + r) * 1024 + k0 + sl * 8);
    }
    {  // O tiles: per option 64 rows x 32 k fp32 -> bf16 (1 float4/thread/option)
      int row = t >> 3, kq = (t & 7) * 4;
      long base = ((long)b * 256 + s2t * 64 + row) * 1024 + k0 + kq;
#pragma unroll
      for (int m = 0; m < 5; m++) {
        const float* Om = m == 0 ? p0 : m == 1 ? p1 : m == 2 ? p2 : m == 3 ? p3 : p4;
        float4 v = *(const float4*)(Om + base);
        bf16x4 h;
        h[0] = (__bf16)v.x; h[1] = (__bf16)v.y; h[2] = (__bf16)v.z; h[3] = (__bf16)v.w;
        *(bf16x4*)&so[m][row][kq] = h;
      }
    }
    __syncthreads();
    bf16x8 qf[5], of[5];
    int sl = l >> 4, lr = l & 15;
#pragma unroll
    for (int m = 0; m < 5; m++) {
      qf[m] = *(const bf16x8*)&sq[m][pr * 16 + lr][sl * 8];
      of[m] = *(const bf16x8*)&so[m][pc * 16 + lr][sl * 8];
    }
#pragma unroll
    for (int i = 0; i < 5; i++) {
#pragma unroll
      for (int n = 0; n < 5; n++) {
        if (n != i)
          acc[PAIR(i, n)] =
              __builtin_amdgcn_mfma_f32_16x16x32_bf16(qf[i], of[n], acc[PAIR(i, n)], 0, 0, 0);
      }
    }
    __syncthreads();
  }
  int s1g = s1t * 32 + pr * 16 + ((l >> 4) << 2);
  int s2g = s2t * 64 + pc * 16 + (l & 15);
#pragma unroll
  for (int r = 0; r < 4; r++) {
    float vacc[5] = {0.f, 0.f, 0.f, 0.f, 0.f};
#pragma unroll
    for (int i = 0; i < 5; i++) {
      float gg[5];
      float mx = -3.0e38f;
#pragma unroll
      for (int n = 0; n < 5; n++)
        if (n != i) { gg[n] = acc[PAIR(i, n)][r]; mx = fmaxf(mx, gg[n]); }
      float ee[5], ssum = 0.f;
#pragma unroll
      for (int n = 0; n < 5; n++)
        if (n != i) { ee[n] = __expf(gg[n] - mx); ssum += ee[n]; }
      float inv = 1.0f / ssum;
#pragma unroll
      for (int n = 0; n < 5; n++)
        if (n != i) vacc[n] += ee[n] * inv;
    }
#pragma unroll
    for (int n = 0; n < 5; n++)
      V[((long)(n * 32 + b) * 256 + s1g + r) * 256 + s2g] = (__bf16)vacc[n];
  }
}

// ---------------------------------------------------------------------------
// out = 0.5 * sum_n V_n @ o_n. A: V rows (bf16, s2-contig). B: o_n fp32
// (s2 x h) transposed in LDS via 4x4 register sub-blocks.
__global__ __launch_bounds__(256) void pvgemm(
    const __bf16* __restrict__ Vb,
    const float* p0, const float* p1, const float* p2, const float* p3, const float* p4,
    float* __restrict__ out)
{
  __shared__ __bf16 smA[128][40];
  __shared__ __bf16 smB[128][40];
  int bid = blockIdx.x;
  int b = bid >> 4, s1t = (bid >> 3) & 1, ht = bid & 7;
  int t = threadIdx.x, l = t & 63, w = t >> 6;
  int wm = w >> 1, wn = w & 1;
  f32x4 acc[4][4] = {};
#pragma unroll
  for (int n = 0; n < 5; n++) {  // compile-time option index (rule #20)
    const float* On = n == 0 ? p0 : n == 1 ? p1 : n == 2 ? p2 : n == 3 ? p3 : p4;
    for (int st2 = 0; st2 < 8; st2++) {
      int s20 = st2 * 32;
#pragma unroll
      for (int p = 0; p < 2; p++) {  // A: V tile 128 x 32 (bf16)
        int c = t + p * 256;
        int row = c >> 2, sl = c & 3;
        *(bf16x8*)&smA[row][sl * 8] =
            *(const bf16x8*)(Vb + (long)(n * BB + b) * SS * SS + (long)(s1t * 128 + row) * SS +
                             s20 + sl * 8);
      }
      {  // B: o_n 32 s2 x 128 h fp32 -> transpose -> smB[h][s2]
        int h4 = (t & 31) * 4, s2q = (t >> 5) * 4;
        const float* src = On + ((long)b * 256 + s20 + s2q) * 1024 + ht * 128 + h4;
        float4 v0 = *(const float4*)(src);
        float4 v1 = *(const float4*)(src + 1024);
        float4 v2 = *(const float4*)(src + 2048);
        float4 v3 = *(const float4*)(src + 3072);
        bf16x4 c0, c1, c2, c3;
        c0[0] = (__bf16)v0.x; c0[1] = (__bf16)v1.x; c0[2] = (__bf16)v2.x; c0[3] = (__bf16)v3.x;
        c1[0] = (__bf16)v0.y; c1[1] = (__bf16)v1.y; c1[2] = (__bf16)v2.y; c1[3] = (__bf16)v3.y;
        c2[0] = (__bf16)v0.z; c2[1] = (__bf16)v1.z; c2[2] = (__bf16)v2.z; c2[3] = (__bf16)v3.z;
        c3[0] = (__bf16)v0.w; c3[1] = (__bf16)v1.w; c3[2] = (__bf16)v2.w; c3[3] = (__bf16)v3.w;
        *(bf16x4*)&smB[h4 + 0][s2q] = c0;
        *(bf16x4*)&smB[h4 + 1][s2q] = c1;
        *(bf16x4*)&smB[h4 + 2][s2q] = c2;
        *(bf16x4*)&smB[h4 + 3][s2q] = c3;
      }
      __syncthreads();
      bf16x8 af[4], bfr[4];
      int sl = l >> 4, lr = l & 15;
#pragma unroll
      for (int i = 0; i < 4; i++) {
        af[i]  = *(const bf16x8*)&smA[wm * 64 + i * 16 + lr][sl * 8];
        bfr[i] = *(const bf16x8*)&smB[wn * 64 + i * 16 + lr][sl * 8];
      }
#pragma unroll
      for (int i = 0; i < 4; i++)
#pragma unroll
        for (int j = 0; j < 4; j++)
          acc[i][j] = __builtin_amdgcn_mfma_f32_16x16x32_bf16(af[i], bfr[j], acc[i][j], 0, 0, 0);
      __syncthreads();
    }
  }
#pragma unroll
  for (int i = 0; i < 4; i++) {
    int m = s1t * 128 + wm * 64 + i * 16 + ((l >> 4) << 2);
#pragma unroll
    for (int j = 0; j < 4; j++) {
      int n = ht * 128 + wn * 64 + j * 16 + (l & 15);
#pragma unroll
      for (int r = 0; r < 4; r++)
        out[(long)(b * SS + m + r) * HH + n] = 0.5f * acc[i][j][r];
    }
  }
}

// ---------------------------------------------------------------------------
extern "C" void kernel_launch(void* const* d_in, const int* in_sizes, int n_in,
                              void* d_out, int out_size, void* d_ws, size_t ws_size,
                              hipStream_t stream)
{
  const size_t SZ_W = (size_t)HH * HH * 2;           //  2 MB
  const size_t SZ_Q = (size_t)5 * BB * SS * HH * 2;  // 84 MB
  const size_t SZ_V = (size_t)5 * BB * SS * SS * 2;  // 21 MB
  const size_t NEED = SZ_W + SZ_Q + SZ_V;            // 107 MB
  if (ws_size < NEED) {  // report ws budget via absmax
    canary<<<1, 1, 0, stream>>>((float*)d_out, (float)(ws_size >> 20));
    return;
  }
  char* ws = (char*)d_ws;
  __bf16* Wt = (__bf16*)ws;
  __bf16* Qb = (__bf16*)(ws + SZ_W);
  __bf16* Vb = (__bf16*)(ws + SZ_W + SZ_Q);
  const float* o0 = (const float*)d_in[0];
  const float* o1 = (const float*)d_in[1];
  const float* o2 = (const float*)d_in[2];
  const float* o3 = (const float*)d_in[3];
  const float* o4 = (const float*)d_in[4];

  cast_trW<<<256, 256, 0, stream>>>((const float*)d_in[5], Wt);
  qgemm<<<dim3(320, 8), 256, 0, stream>>>(o0, o1, o2, o3, o4, Wt, Qb);
  gram_softmax<<<1024, 512, 0, stream>>>(Qb, o0, o1, o2, o3, o4, Vb);
  pvgemm<<<512, 256, 0, stream>>>(Vb, o0, o1, o2, o3, o4, (float*)d_out);
}

// Round 4
// 393.622 us; speedup vs baseline: 1.0232x; 1.0232x over previous
//
#include <hip/hip_runtime.h>
#include <hip/hip_bf16.h>
#include <stdint.h>

// Problem: b=32, s=256, h=1024, 5 options.
// out = 0.5 * sum_n V_n @ o_n,  V_n = sum_{i!=n} softmax_k(q_i . o_k)_n,  q_i = o_i @ W
// bias is softmax-shift-invariant -> ignored.
// Round 4: ws in [107MB, 275MB). Fast path (needs 191MB): cast Obf once, m97-style
// qgemm (global_load_lds, linear LDS), gload_lds gram staging. Fallback = round-3.

#define BB 32
#define SS 256
#define HH 1024

typedef __attribute__((ext_vector_type(4))) float f32x4;
typedef __attribute__((ext_vector_type(8))) __bf16 bf16x8;
typedef __attribute__((ext_vector_type(4))) __bf16 bf16x4;

__device__ constexpr int PAIR(int i, int n) { return i * 4 + (n > i ? n - 1 : n); }

__device__ __forceinline__ void gload_lds16(const void* g, void* l) {
  __builtin_amdgcn_global_load_lds((const __attribute__((address_space(1))) void*)g,
                                   (__attribute__((address_space(3))) void*)l, 16, 0, 0);
}

__global__ void canary(float* out, float v) { out[0] = v; }

// ---------------------------------------------------------------------------
// fp32 -> bf16 flat cast of the 5 options into Obf[m][b][s][h].
__global__ __launch_bounds__(256) void cast_all(
    const float* p0, const float* p1, const float* p2, const float* p3, const float* p4,
    __bf16* __restrict__ dst)
{
  int m = blockIdx.x >> 12;
  long off = ((long)(blockIdx.x & 4095) * 256 + threadIdx.x) * 8;
  const float* src = m == 0 ? p0 : m == 1 ? p1 : m == 2 ? p2 : m == 3 ? p3 : p4;
  float4 v0 = *(const float4*)(src + off);
  float4 v1 = *(const float4*)(src + off + 4);
  bf16x8 h;
  h[0] = (__bf16)v0.x; h[1] = (__bf16)v0.y; h[2] = (__bf16)v0.z; h[3] = (__bf16)v0.w;
  h[4] = (__bf16)v1.x; h[5] = (__bf16)v1.y; h[6] = (__bf16)v1.z; h[7] = (__bf16)v1.w;
  *(bf16x8*)(dst + (long)m * BB * SS * HH + off) = h;
}

// ---------------------------------------------------------------------------
// W (1024x1024 fp32) -> Wt (bf16, transposed). 64x64 tiles, grid 256.
__global__ __launch_bounds__(256) void cast_trW(const float* __restrict__ src,
                                                __bf16* __restrict__ dstT)
{
  __shared__ __bf16 tile[64][72];
  int ct = blockIdx.x & 15, rt = blockIdx.x >> 4;
  const float* s = src + (long)(rt * 64) * 1024 + ct * 64;
  int t = threadIdx.x;
#pragma unroll
  for (int p = 0; p < 4; p++) {
    int c = t + p * 256;
    int row = c >> 4, c4 = c & 15;
    float4 v = *(const float4*)(s + (long)row * 1024 + c4 * 4);
    bf16x4 h;
    h[0] = (__bf16)v.x; h[1] = (__bf16)v.y; h[2] = (__bf16)v.z; h[3] = (__bf16)v.w;
    *(bf16x4*)&tile[row][c4 * 4] = h;
  }
  __syncthreads();
#pragma unroll
  for (int p = 0; p < 4; p++) {
    int c = t + p * 256;
    int hr = c >> 4, s4 = c & 15;
    bf16x4 h;
    h[0] = tile[s4 * 4 + 0][hr];
    h[1] = tile[s4 * 4 + 1][hr];
    h[2] = tile[s4 * 4 + 2][hr];
    h[3] = tile[s4 * 4 + 3][hr];
    *(bf16x4*)(dstT + (long)(ct * 64 + hr) * 1024 + rt * 64 + s4 * 4) = h;
  }
}

// ---------------------------------------------------------------------------
// FAST PATH qgemm: Q = Obf @ Wt^T-form. m97 structure: 128x128 tile, BK=32,
// global_load_lds width 16, linear LDS [128][32] bf16, 16 MFMA / K-step.
__global__ __launch_bounds__(256) void qgemm_b16(
    const __bf16* __restrict__ A, const __bf16* __restrict__ Bt, __bf16* __restrict__ C)
{
  __shared__ __align__(16) __bf16 smA[128][32];
  __shared__ __align__(16) __bf16 smB[128][32];
  int rt = blockIdx.x, ct = blockIdx.y;
  int t = threadIdx.x, l = t & 63, w = t >> 6;
  int wm = w >> 1, wn = w & 1;
  f32x4 acc[4][4] = {};
  for (int k0 = 0; k0 < 1024; k0 += 32) {
#pragma unroll
    for (int p = 0; p < 2; p++) {
      int c = t + p * 256;                       // 16B chunk id, 512 per tile
      int row = c >> 2, half = c & 3;            // 4 chunks per 32-k row
      gload_lds16(A + (long)(rt * 128 + row) * 1024 + k0 + half * 8,
                  (char*)smA + ((c >> 6) << 10));
      gload_lds16(Bt + (long)(ct * 128 + row) * 1024 + k0 + half * 8,
                  (char*)smB + ((c >> 6) << 10));
    }
    __syncthreads();
    bf16x8 af[4], bfr[4];
    int sl = l >> 4, lr = l & 15;
#pragma unroll
    for (int i = 0; i < 4; i++) {
      af[i]  = *(const bf16x8*)&smA[wm * 64 + i * 16 + lr][sl * 8];
      bfr[i] = *(const bf16x8*)&smB[wn * 64 + i * 16 + lr][sl * 8];
    }
#pragma unroll
    for (int i = 0; i < 4; i++)
#pragma unroll
      for (int j = 0; j < 4; j++)
        acc[i][j] = __builtin_amdgcn_mfma_f32_16x16x32_bf16(af[i], bfr[j], acc[i][j], 0, 0, 0);
    __syncthreads();
  }
#pragma unroll
  for (int i = 0; i < 4; i++) {
    long mrow = (long)rt * 128 + wm * 64 + i * 16 + ((l >> 4) << 2);
#pragma unroll
    for (int j = 0; j < 4; j++) {
      int n = ct * 128 + wn * 64 + j * 16 + (l & 15);
#pragma unroll
      for (int r = 0; r < 4; r++)
        C[(mrow + r) * 1024 + n] = (__bf16)acc[i][j][r];
    }
  }
}

// ---------------------------------------------------------------------------
// FAST PATH gram: 20 cross-grams + lane-local softmax -> V. gload_lds staging.
// Block 512 thr (8 waves, 2x4 patches of 16x16) covers 32 s1 x 64 s2.
__global__ __launch_bounds__(512) void gram_b16(
    const __bf16* __restrict__ Q, const __bf16* __restrict__ O, __bf16* __restrict__ V)
{
  __shared__ __align__(16) __bf16 sq[5][32][32];  // 10 KB
  __shared__ __align__(16) __bf16 so[5][64][32];  // 20 KB
  int bid = blockIdx.x;
  int b = bid >> 5, s1t = (bid >> 2) & 7, s2t = bid & 3;
  int t = threadIdx.x, l = t & 63, w = t >> 6;
  int pr = w >> 2, pc = w & 3;
  f32x4 acc[20] = {};
  for (int k0 = 0; k0 < 1024; k0 += 32) {
    for (int c = t; c < 640; c += 512) {   // Q: 5 options x 32 rows x 4 chunks
      int m = c >> 7, j = c & 127, r = j >> 2, half = j & 3;
      gload_lds16(Q + ((long)(m * 32 + b) * 256 + s1t * 32 + r) * 1024 + k0 + half * 8,
                  (char*)sq + ((c >> 6) << 10));
    }
    for (int c = t; c < 1280; c += 512) {  // O: 5 options x 64 rows x 4 chunks
      int m = c >> 8, j = c & 255, r = j >> 2, half = j & 3;
      gload_lds16(O + ((long)(m * 32 + b) * 256 + s2t * 64 + r) * 1024 + k0 + half * 8,
                  (char*)so + ((c >> 6) << 10));
    }
    __syncthreads();
    bf16x8 qf[5], of[5];
    int sl = l >> 4, lr = l & 15;
#pragma unroll
    for (int m = 0; m < 5; m++) {
      qf[m] = *(const bf16x8*)&sq[m][pr * 16 + lr][sl * 8];
      of[m] = *(const bf16x8*)&so[m][pc * 16 + lr][sl * 8];
    }
#pragma unroll
    for (int i = 0; i < 5; i++) {
#pragma unroll
      for (int n = 0; n < 5; n++) {
        if (n != i)
          acc[PAIR(i, n)] =
              __builtin_amdgcn_mfma_f32_16x16x32_bf16(qf[i], of[n], acc[PAIR(i, n)], 0, 0, 0);
      }
    }
    __syncthreads();
  }
  int s1g = s1t * 32 + pr * 16 + ((l >> 4) << 2);
  int s2g = s2t * 64 + pc * 16 + (l & 15);
#pragma unroll
  for (int r = 0; r < 4; r++) {
    float vacc[5] = {0.f, 0.f, 0.f, 0.f, 0.f};
#pragma unroll
    for (int i = 0; i < 5; i++) {
      float gg[5];
      float mx = -3.0e38f;
#pragma unroll
      for (int n = 0; n < 5; n++)
        if (n != i) { gg[n] = acc[PAIR(i, n)][r]; mx = fmaxf(mx, gg[n]); }
      float ee[5], ssum = 0.f;
#pragma unroll
      for (int n = 0; n < 5; n++)
        if (n != i) { ee[n] = __expf(gg[n] - mx); ssum += ee[n]; }
      float inv = 1.0f / ssum;
#pragma unroll
      for (int n = 0; n < 5; n++)
        if (n != i) vacc[n] += ee[n] * inv;
    }
#pragma unroll
    for (int n = 0; n < 5; n++)
      V[((long)(n * 32 + b) * 256 + s1g + r) * 256 + s2g] = (__bf16)vacc[n];
  }
}

// ---------------------------------------------------------------------------
// FALLBACK qgemm (round-3, proven): fp32 A staged with cast.
__global__ __launch_bounds__(256) void qgemm(
    const float* p0, const float* p1, const float* p2, const float* p3, const float* p4,
    const __bf16* __restrict__ Bt, __bf16* __restrict__ C)
{
  __shared__ __bf16 smA[128][40];
  __shared__ __bf16 smB[128][40];
  int rt = blockIdx.x, ct = blockIdx.y;
  int m = rt >> 6;
  const float* A32 = m == 0 ? p0 : m == 1 ? p1 : m == 2 ? p2 : m == 3 ? p3 : p4;
  long rbase = (long)(rt & 63) * 128;
  int t = threadIdx.x, l = t & 63, w = t >> 6;
  int wm = w >> 1, wn = w & 1;
  f32x4 acc[4][4] = {};
  for (int k0 = 0; k0 < 1024; k0 += 32) {
    {
      int row = t >> 1, half = (t & 1) * 16;
      const float* src = A32 + (rbase + row) * 1024 + k0 + half;
      float4 v0 = *(const float4*)(src);
      float4 v1 = *(const float4*)(src + 4);
      float4 v2 = *(const float4*)(src + 8);
      float4 v3 = *(const float4*)(src + 12);
      bf16x8 h0, h1;
      h0[0] = (__bf16)v0.x; h0[1] = (__bf16)v0.y; h0[2] = (__bf16)v0.z; h0[3] = (__bf16)v0.w;
      h0[4] = (__bf16)v1.x; h0[5] = (__bf16)v1.y; h0[6] = (__bf16)v1.z; h0[7] = (__bf16)v1.w;
      h1[0] = (__bf16)v2.x; h1[1] = (__bf16)v2.y; h1[2] = (__bf16)v2.z; h1[3] = (__bf16)v2.w;
      h1[4] = (__bf16)v3.x; h1[5] = (__bf16)v3.y; h1[6] = (__bf16)v3.z; h1[7] = (__bf16)v3.w;
      *(bf16x8*)&smA[row][half] = h0;
      *(bf16x8*)&smA[row][half + 8] = h1;
    }
#pragma unroll
    for (int p = 0; p < 2; p++) {
      int c = t + p * 256;
      int row = c >> 2, sl = c & 3;
      *(bf16x8*)&smB[row][sl * 8] =
          *(const bf16x8*)(Bt + (long)(ct * 128 + row) * 1024 + k0 + sl * 8);
    }
    __syncthreads();
    bf16x8 af[4], bfr[4];
    int sl = l >> 4, lr = l & 15;
#pragma unroll
    for (int i = 0; i < 4; i++) {
      af[i]  = *(const bf16x8*)&smA[wm * 64 + i * 16 + lr][sl * 8];
      bfr[i] = *(const bf16x8*)&smB[wn * 64 + i * 16 + lr][sl * 8];
    }
#pragma unroll
    for (int i = 0; i < 4; i++)
#pragma unroll
      for (int j = 0; j < 4; j++)
        acc[i][j] = __builtin_amdgcn_mfma_f32_16x16x32_bf16(af[i], bfr[j], acc[i][j], 0, 0, 0);
    __syncthreads();
  }
#pragma unroll
  for (int i = 0; i < 4; i++) {
    long mrow = (long)rt * 128 + wm * 64 + i * 16 + ((l >> 4) << 2);
#pragma unroll
    for (int j = 0; j < 4; j++) {
      int n = ct * 128 + wn * 64 + j * 16 + (l & 15);
#pragma unroll
      for (int r = 0; r < 4; r++)
        C[(mrow + r) * 1024 + n] = (__bf16)acc[i][j][r];
    }
  }
}

// ---------------------------------------------------------------------------
// FALLBACK gram (round-3, proven): O staged from fp32.
__global__ __launch_bounds__(512) void gram_softmax(
    const __bf16* __restrict__ Q,
    const float* p0, const float* p1, const float* p2, const float* p3, const float* p4,
    __bf16* __restrict__ V)
{
  __shared__ __bf16 sq[5][32][40];
  __shared__ __bf16 so[5][64][40];
  int bid = blockIdx.x;
  int b = bid >> 5, s1t = (bid >> 2) & 7, s2t = bid & 3;
  int t = threadIdx.x, l = t & 63, w = t >> 6;
  int pr = w >> 2, pc = w & 3;
  f32x4 acc[20] = {};
  for (int k0 = 0; k0 < 1024; k0 += 32) {
    for (int c = t; c < 640; c += 512) {
      int m = c >> 7, r = (c >> 2) & 31, sl = c & 3;
      *(bf16x8*)&sq[m][r][sl * 8] =
          *(const bf16x8*)(Q + ((long)(m * 32 + b) * 256 + s1t * 32 + r) * 1024 + k0 + sl * 8);
    }
    {
      int row = t >> 3, kq = (t & 7) * 4;
      long base = ((long)b * 256 + s2t * 64 + row) * 1024 + k0 + kq;
#pragma unroll
      for (int m = 0; m < 5; m++) {
        const float* Om = m == 0 ? p0 : m == 1 ? p1 : m == 2 ? p2 : m == 3 ? p3 : p4;
        float4 v = *(const float4*)(Om + base);
        bf16x4 h;
        h[0] = (__bf16)v.x; h[1] = (__bf16)v.y; h[2] = (__bf16)v.z; h[3] = (__bf16)v.w;
        *(bf16x4*)&so[m][row][kq] = h;
      }
    }
    __syncthreads();
    bf16x8 qf[5], of[5];
    int sl = l >> 4, lr = l & 15;
#pragma unroll
    for (int m = 0; m < 5; m++) {
      qf[m] = *(const bf16x8*)&sq[m][pr * 16 + lr][sl * 8];
      of[m] = *(const bf16x8*)&so[m][pc * 16 + lr][sl * 8];
    }
#pragma unroll
    for (int i = 0; i < 5; i++) {
#pragma unroll
      for (int n = 0; n < 5; n++) {
        if (n != i)
          acc[PAIR(i, n)] =
              __builtin_amdgcn_mfma_f32_16x16x32_bf16(qf[i], of[n], acc[PAIR(i, n)], 0, 0, 0);
      }
    }
    __syncthreads();
  }
  int s1g = s1t * 32 + pr * 16 + ((l >> 4) << 2);
  int s2g = s2t * 64 + pc * 16 + (l & 15);
#pragma unroll
  for (int r = 0; r < 4; r++) {
    float vacc[5] = {0.f, 0.f, 0.f, 0.f, 0.f};
#pragma unroll
    for (int i = 0; i < 5; i++) {
      float gg[5];
      float mx = -3.0e38f;
#pragma unroll
      for (int n = 0; n < 5; n++)
        if (n != i) { gg[n] = acc[PAIR(i, n)][r]; mx = fmaxf(mx, gg[n]); }
      float ee[5], ssum = 0.f;
#pragma unroll
      for (int n = 0; n < 5; n++)
        if (n != i) { ee[n] = __expf(gg[n] - mx); ssum += ee[n]; }
      float inv = 1.0f / ssum;
#pragma unroll
      for (int n = 0; n < 5; n++)
        if (n != i) vacc[n] += ee[n] * inv;
    }
#pragma unroll
    for (int n = 0; n < 5; n++)
      V[((long)(n * 32 + b) * 256 + s1g + r) * 256 + s2g] = (__bf16)vacc[n];
  }
}

// ---------------------------------------------------------------------------
// out = 0.5 * sum_n V_n @ o_n (per batch). B = o_n fp32, transposed in LDS.
__global__ __launch_bounds__(256) void pvgemm(
    const __bf16* __restrict__ Vb,
    const float* p0, const float* p1, const float* p2, const float* p3, const float* p4,
    float* __restrict__ out)
{
  __shared__ __bf16 smA[128][40];
  __shared__ __bf16 smB[128][40];
  int bid = blockIdx.x;
  int b = bid >> 4, s1t = (bid >> 3) & 1, ht = bid & 7;
  int t = threadIdx.x, l = t & 63, w = t >> 6;
  int wm = w >> 1, wn = w & 1;
  f32x4 acc[4][4] = {};
#pragma unroll
  for (int n = 0; n < 5; n++) {
    const float* On = n == 0 ? p0 : n == 1 ? p1 : n == 2 ? p2 : n == 3 ? p3 : p4;
    for (int st2 = 0; st2 < 8; st2++) {
      int s20 = st2 * 32;
#pragma unroll
      for (int p = 0; p < 2; p++) {
        int c = t + p * 256;
        int row = c >> 2, sl = c & 3;
        *(bf16x8*)&smA[row][sl * 8] =
            *(const bf16x8*)(Vb + (long)(n * BB + b) * SS * SS + (long)(s1t * 128 + row) * SS +
                             s20 + sl * 8);
      }
      {
        int h4 = (t & 31) * 4, s2q = (t >> 5) * 4;
        const float* src = On + ((long)b * 256 + s20 + s2q) * 1024 + ht * 128 + h4;
        float4 v0 = *(const float4*)(src);
        float4 v1 = *(const float4*)(src + 1024);
        float4 v2 = *(const float4*)(src + 2048);
        float4 v3 = *(const float4*)(src + 3072);
        bf16x4 c0, c1, c2, c3;
        c0[0] = (__bf16)v0.x; c0[1] = (__bf16)v1.x; c0[2] = (__bf16)v2.x; c0[3] = (__bf16)v3.x;
        c1[0] = (__bf16)v0.y; c1[1] = (__bf16)v1.y; c1[2] = (__bf16)v2.y; c1[3] = (__bf16)v3.y;
        c2[0] = (__bf16)v0.z; c2[1] = (__bf16)v1.z; c2[2] = (__bf16)v2.z; c2[3] = (__bf16)v3.z;
        c3[0] = (__bf16)v0.w; c3[1] = (__bf16)v1.w; c3[2] = (__bf16)v2.w; c3[3] = (__bf16)v3.w;
        *(bf16x4*)&smB[h4 + 0][s2q] = c0;
        *(bf16x4*)&smB[h4 + 1][s2q] = c1;
        *(bf16x4*)&smB[h4 + 2][s2q] = c2;
        *(bf16x4*)&smB[h4 + 3][s2q] = c3;
      }
      __syncthreads();
      bf16x8 af[4], bfr[4];
      int sl = l >> 4, lr = l & 15;
#pragma unroll
      for (int i = 0; i < 4; i++) {
        af[i]  = *(const bf16x8*)&smA[wm * 64 + i * 16 + lr][sl * 8];
        bfr[i] = *(const bf16x8*)&smB[wn * 64 + i * 16 + lr][sl * 8];
      }
#pragma unroll
      for (int i = 0; i < 4; i++)
#pragma unroll
        for (int j = 0; j < 4; j++)
          acc[i][j] = __builtin_amdgcn_mfma_f32_16x16x32_bf16(af[i], bfr[j], acc[i][j], 0, 0, 0);
      __syncthreads();
    }
  }
#pragma unroll
  for (int i = 0; i < 4; i++) {
    int m = s1t * 128 + wm * 64 + i * 16 + ((l >> 4) << 2);
#pragma unroll
    for (int j = 0; j < 4; j++) {
      int n = ht * 128 + wn * 64 + j * 16 + (l & 15);
#pragma unroll
      for (int r = 0; r < 4; r++)
        out[(long)(b * SS + m + r) * HH + n] = 0.5f * acc[i][j][r];
    }
  }
}

// ---------------------------------------------------------------------------
extern "C" void kernel_launch(void* const* d_in, const int* in_sizes, int n_in,
                              void* d_out, int out_size, void* d_ws, size_t ws_size,
                              hipStream_t stream)
{
  const size_t SZ_W = (size_t)HH * HH * 2;           //  2 MB
  const size_t SZ_Q = (size_t)5 * BB * SS * HH * 2;  // 84 MB
  const size_t SZ_V = (size_t)5 * BB * SS * SS * 2;  // 21 MB
  const size_t SZ_O = (size_t)5 * BB * SS * HH * 2;  // 84 MB
  const size_t NEED_SMALL = SZ_W + SZ_Q + SZ_V;      // 107 MB
  const size_t NEED_BIG = NEED_SMALL + SZ_O;         // 191 MB
  if (ws_size < NEED_SMALL) {
    canary<<<1, 1, 0, stream>>>((float*)d_out, (float)(ws_size >> 20));
    return;
  }
  char* ws = (char*)d_ws;
  __bf16* Wt  = (__bf16*)ws;
  __bf16* Qb  = (__bf16*)(ws + SZ_W);
  __bf16* Vb  = (__bf16*)(ws + SZ_W + SZ_Q);
  __bf16* Obf = (__bf16*)(ws + SZ_W + SZ_Q + SZ_V);
  const float* o0 = (const float*)d_in[0];
  const float* o1 = (const float*)d_in[1];
  const float* o2 = (const float*)d_in[2];
  const float* o3 = (const float*)d_in[3];
  const float* o4 = (const float*)d_in[4];

  cast_trW<<<256, 256, 0, stream>>>((const float*)d_in[5], Wt);
  if (ws_size >= NEED_BIG) {
    cast_all<<<5 * 4096, 256, 0, stream>>>(o0, o1, o2, o3, o4, Obf);
    qgemm_b16<<<dim3(320, 8), 256, 0, stream>>>(Obf, Wt, Qb);
    gram_b16<<<1024, 512, 0, stream>>>(Qb, Obf, Vb);
  } else {
    qgemm<<<dim3(320, 8), 256, 0, stream>>>(o0, o1, o2, o3, o4, Wt, Qb);
    gram_softmax<<<1024, 512, 0, stream>>>(Qb, o0, o1, o2, o3, o4, Vb);
  }
  pvgemm<<<512, 256, 0, stream>>>(Vb, o0, o1, o2, o3, o4, (float*)d_out);
}

// Round 5
// 354.487 us; speedup vs baseline: 1.1362x; 1.1104x over previous
//
#include <hip/hip_runtime.h>
#include <hip/hip_bf16.h>
#include <stdint.h>

// Problem: b=32, s=256, h=1024, 5 options.
// out = 0.5 * sum_n V_n @ o_n,  V_n = sum_{i!=n} softmax_k(q_i . o_k)_n,  q_i = o_i @ W
// bias is softmax-shift-invariant -> ignored.
// Round 5: ws >= 191MB proven. gram rebuilt: 4-wave blocks (3 blocks/CU vs 1)
// + 2-phase double-buffered staging (T3-minimum). pvgemm B-operand now bf16.

#define BB 32
#define SS 256
#define HH 1024

typedef __attribute__((ext_vector_type(4))) float f32x4;
typedef __attribute__((ext_vector_type(8))) __bf16 bf16x8;
typedef __attribute__((ext_vector_type(4))) __bf16 bf16x4;

__device__ constexpr int PAIR(int i, int n) { return i * 4 + (n > i ? n - 1 : n); }

__device__ __forceinline__ void gload_lds16(const void* g, void* l) {
  __builtin_amdgcn_global_load_lds((const __attribute__((address_space(1))) void*)g,
                                   (__attribute__((address_space(3))) void*)l, 16, 0, 0);
}

__global__ void canary(float* out, float v) { out[0] = v; }

// ---------------------------------------------------------------------------
// fp32 -> bf16 flat cast of the 5 options into Obf[m][b][s][h].
__global__ __launch_bounds__(256) void cast_all(
    const float* p0, const float* p1, const float* p2, const float* p3, const float* p4,
    __bf16* __restrict__ dst)
{
  int m = blockIdx.x >> 12;
  long off = ((long)(blockIdx.x & 4095) * 256 + threadIdx.x) * 8;
  const float* src = m == 0 ? p0 : m == 1 ? p1 : m == 2 ? p2 : m == 3 ? p3 : p4;
  float4 v0 = *(const float4*)(src + off);
  float4 v1 = *(const float4*)(src + off + 4);
  bf16x8 h;
  h[0] = (__bf16)v0.x; h[1] = (__bf16)v0.y; h[2] = (__bf16)v0.z; h[3] = (__bf16)v0.w;
  h[4] = (__bf16)v1.x; h[5] = (__bf16)v1.y; h[6] = (__bf16)v1.z; h[7] = (__bf16)v1.w;
  *(bf16x8*)(dst + (long)m * BB * SS * HH + off) = h;
}

// ---------------------------------------------------------------------------
// W (1024x1024 fp32) -> Wt (bf16, transposed). 64x64 tiles, grid 256.
__global__ __launch_bounds__(256) void cast_trW(const float* __restrict__ src,
                                                __bf16* __restrict__ dstT)
{
  __shared__ __bf16 tile[64][72];
  int ct = blockIdx.x & 15, rt = blockIdx.x >> 4;
  const float* s = src + (long)(rt * 64) * 1024 + ct * 64;
  int t = threadIdx.x;
#pragma unroll
  for (int p = 0; p < 4; p++) {
    int c = t + p * 256;
    int row = c >> 4, c4 = c & 15;
    float4 v = *(const float4*)(s + (long)row * 1024 + c4 * 4);
    bf16x4 h;
    h[0] = (__bf16)v.x; h[1] = (__bf16)v.y; h[2] = (__bf16)v.z; h[3] = (__bf16)v.w;
    *(bf16x4*)&tile[row][c4 * 4] = h;
  }
  __syncthreads();
#pragma unroll
  for (int p = 0; p < 4; p++) {
    int c = t + p * 256;
    int hr = c >> 4, s4 = c & 15;
    bf16x4 h;
    h[0] = tile[s4 * 4 + 0][hr];
    h[1] = tile[s4 * 4 + 1][hr];
    h[2] = tile[s4 * 4 + 2][hr];
    h[3] = tile[s4 * 4 + 3][hr];
    *(bf16x4*)(dstT + (long)(ct * 64 + hr) * 1024 + rt * 64 + s4 * 4) = h;
  }
}

// ---------------------------------------------------------------------------
// qgemm: Q = Obf @ Wt. m97 structure: 128x128 tile, BK=32, global_load_lds
// width 16, linear LDS [128][32] bf16, 16 MFMA / K-step, 3 blocks/CU.
__global__ __launch_bounds__(256) void qgemm_b16(
    const __bf16* __restrict__ A, const __bf16* __restrict__ Bt, __bf16* __restrict__ C)
{
  __shared__ __align__(16) __bf16 smA[128][32];
  __shared__ __align__(16) __bf16 smB[128][32];
  int rt = blockIdx.x, ct = blockIdx.y;
  int t = threadIdx.x, l = t & 63, w = t >> 6;
  int wm = w >> 1, wn = w & 1;
  f32x4 acc[4][4] = {};
  for (int k0 = 0; k0 < 1024; k0 += 32) {
#pragma unroll
    for (int p = 0; p < 2; p++) {
      int c = t + p * 256;
      int row = c >> 2, half = c & 3;
      gload_lds16(A + (long)(rt * 128 + row) * 1024 + k0 + half * 8,
                  (char*)smA + ((c >> 6) << 10));
      gload_lds16(Bt + (long)(ct * 128 + row) * 1024 + k0 + half * 8,
                  (char*)smB + ((c >> 6) << 10));
    }
    __syncthreads();
    bf16x8 af[4], bfr[4];
    int sl = l >> 4, lr = l & 15;
#pragma unroll
    for (int i = 0; i < 4; i++) {
      af[i]  = *(const bf16x8*)&smA[wm * 64 + i * 16 + lr][sl * 8];
      bfr[i] = *(const bf16x8*)&smB[wn * 64 + i * 16 + lr][sl * 8];
    }
#pragma unroll
    for (int i = 0; i < 4; i++)
#pragma unroll
      for (int j = 0; j < 4; j++)
        acc[i][j] = __builtin_amdgcn_mfma_f32_16x16x32_bf16(af[i], bfr[j], acc[i][j], 0, 0, 0);
    __syncthreads();
  }
#pragma unroll
  for (int i = 0; i < 4; i++) {
    long mrow = (long)rt * 128 + wm * 64 + i * 16 + ((l >> 4) << 2);
#pragma unroll
    for (int j = 0; j < 4; j++) {
      int n = ct * 128 + wn * 64 + j * 16 + (l & 15);
#pragma unroll
      for (int r = 0; r < 4; r++)
        C[(mrow + r) * 1024 + n] = (__bf16)acc[i][j][r];
    }
  }
}

// ---------------------------------------------------------------------------
// gram: 20 cross-grams + lane-local softmax -> V. 256 thr (4 waves, 2x2
// patches of 16x16) covers 32 s1 x 32 s2. Double-buffered 2-phase staging:
// issue K-step t+1 DMA before computing t; one barrier per step.
__global__ __launch_bounds__(256) void gram_b16(
    const __bf16* __restrict__ Q, const __bf16* __restrict__ O, __bf16* __restrict__ V)
{
  __shared__ __align__(16) __bf16 sq[2][5][32][32];  // 2 x 10 KB
  __shared__ __align__(16) __bf16 so[2][5][32][32];  // 2 x 10 KB
  int bid = blockIdx.x;
  int b = bid >> 6, s1t = (bid >> 3) & 7, s2t = bid & 7;
  int t = threadIdx.x, l = t & 63, w = t >> 6;
  int pr = w >> 1, pc = w & 1;
  f32x4 acc[20] = {};

  long qrow0 = (long)b * 256 + s1t * 32;  // option-m row offset added per-chunk
  long orow0 = (long)b * 256 + s2t * 32;

  // Stage one K-step (32 k) into buffer `buf`: 5 options x 32 rows x 4 chunks
  // each for Q and O; chunk id c: m=c>>7, r=(c&127)>>2, half=c&3.
  // Tail (c in [512,640)) is waves 0-1 fully active -> wave-uniform LDS base.
#define GRAM_STAGE(buf, k0)                                                          \
  for (int c = t; c < 640; c += 256) {                                               \
    int m = c >> 7, j = c & 127, r = j >> 2, half = j & 3;                           \
    gload_lds16(Q + ((long)m * BB * SS + qrow0 + r) * 1024 + (k0) + half * 8,        \
                (char*)sq + (buf) * 10240 + ((c >> 6) << 10));                       \
    gload_lds16(O + ((long)m * BB * SS + orow0 + r) * 1024 + (k0) + half * 8,        \
                (char*)so + (buf) * 10240 + ((c >> 6) << 10));                       \
  }

  GRAM_STAGE(0, 0);
  __syncthreads();
  for (int ks = 0; ks < 32; ks++) {
    int cur = ks & 1;
    if (ks < 31) { GRAM_STAGE(cur ^ 1, (ks + 1) * 32); }
    bf16x8 qf[5], of[5];
    int sl = l >> 4, lr = l & 15;
#pragma unroll
    for (int m = 0; m < 5; m++) {
      qf[m] = *(const bf16x8*)&sq[cur][m][pr * 16 + lr][sl * 8];
      of[m] = *(const bf16x8*)&so[cur][m][pc * 16 + lr][sl * 8];
    }
#pragma unroll
    for (int i = 0; i < 5; i++) {
#pragma unroll
      for (int n = 0; n < 5; n++) {
        if (n != i)
          acc[PAIR(i, n)] =
              __builtin_amdgcn_mfma_f32_16x16x32_bf16(qf[i], of[n], acc[PAIR(i, n)], 0, 0, 0);
      }
    }
    __syncthreads();  // drains vmcnt (next-step DMA) + lgkmcnt (our ds_reads)
  }
#undef GRAM_STAGE

  int s1g = s1t * 32 + pr * 16 + ((l >> 4) << 2);
  int s2g = s2t * 32 + pc * 16 + (l & 15);
#pragma unroll
  for (int r = 0; r < 4; r++) {
    float vacc[5] = {0.f, 0.f, 0.f, 0.f, 0.f};
#pragma unroll
    for (int i = 0; i < 5; i++) {
      float gg[5];
      float mx = -3.0e38f;
#pragma unroll
      for (int n = 0; n < 5; n++)
        if (n != i) { gg[n] = acc[PAIR(i, n)][r]; mx = fmaxf(mx, gg[n]); }
      float ee[5], ssum = 0.f;
#pragma unroll
      for (int n = 0; n < 5; n++)
        if (n != i) { ee[n] = __expf(gg[n] - mx); ssum += ee[n]; }
      float inv = 1.0f / ssum;
#pragma unroll
      for (int n = 0; n < 5; n++)
        if (n != i) vacc[n] += ee[n] * inv;
    }
#pragma unroll
    for (int n = 0; n < 5; n++)
      V[((long)(n * 32 + b) * 256 + s1g + r) * 256 + s2g] = (__bf16)vacc[n];
  }
}

// ---------------------------------------------------------------------------
// out = 0.5 * sum_n V_n @ o_n (per batch). A: V rows (bf16, s2-contig).
// B: Obf bf16 (s2 x h), transposed in LDS via 4x4 register sub-blocks.
__global__ __launch_bounds__(256) void pvgemm(
    const __bf16* __restrict__ Vb, const __bf16* __restrict__ Obf, float* __restrict__ out)
{
  __shared__ __bf16 smA[128][40];
  __shared__ __bf16 smB[128][40];
  int bid = blockIdx.x;
  int b = bid >> 4, s1t = (bid >> 3) & 1, ht = bid & 7;
  int t = threadIdx.x, l = t & 63, w = t >> 6;
  int wm = w >> 1, wn = w & 1;
  f32x4 acc[4][4] = {};
#pragma unroll
  for (int n = 0; n < 5; n++) {
    const __bf16* On = Obf + (long)n * BB * SS * HH;
    for (int st2 = 0; st2 < 8; st2++) {
      int s20 = st2 * 32;
#pragma unroll
      for (int p = 0; p < 2; p++) {  // A: V tile 128 x 32 (bf16)
        int c = t + p * 256;
        int row = c >> 2, sl = c & 3;
        *(bf16x8*)&smA[row][sl * 8] =
            *(const bf16x8*)(Vb + (long)(n * BB + b) * SS * SS + (long)(s1t * 128 + row) * SS +
                             s20 + sl * 8);
      }
      {  // B: 32 s2-rows x 128 h (bf16) -> transpose -> smB[h][s2]
        int h4 = (t & 31) * 4, s2q = (t >> 5) * 4;
        const __bf16* src = On + ((long)b * 256 + s20 + s2q) * 1024 + ht * 128 + h4;
        bf16x4 v0 = *(const bf16x4*)(src);
        bf16x4 v1 = *(const bf16x4*)(src + 1024);
        bf16x4 v2 = *(const bf16x4*)(src + 2048);
        bf16x4 v3 = *(const bf16x4*)(src + 3072);
        bf16x4 c0, c1, c2, c3;
        c0[0] = v0[0]; c0[1] = v1[0]; c0[2] = v2[0]; c0[3] = v3[0];
        c1[0] = v0[1]; c1[1] = v1[1]; c1[2] = v2[1]; c1[3] = v3[1];
        c2[0] = v0[2]; c2[1] = v1[2]; c2[2] = v2[2]; c2[3] = v3[2];
        c3[0] = v0[3]; c3[1] = v1[3]; c3[2] = v2[3]; c3[3] = v3[3];
        *(bf16x4*)&smB[h4 + 0][s2q] = c0;
        *(bf16x4*)&smB[h4 + 1][s2q] = c1;
        *(bf16x4*)&smB[h4 + 2][s2q] = c2;
        *(bf16x4*)&smB[h4 + 3][s2q] = c3;
      }
      __syncthreads();
      bf16x8 af[4], bfr[4];
      int sl = l >> 4, lr = l & 15;
#pragma unroll
      for (int i = 0; i < 4; i++) {
        af[i]  = *(const bf16x8*)&smA[wm * 64 + i * 16 + lr][sl * 8];
        bfr[i] = *(const bf16x8*)&smB[wn * 64 + i * 16 + lr][sl * 8];
      }
#pragma unroll
      for (int i = 0; i < 4; i++)
#pragma unroll
        for (int j = 0; j < 4; j++)
          acc[i][j] = __builtin_amdgcn_mfma_f32_16x16x32_bf16(af[i], bfr[j], acc[i][j], 0, 0, 0);
      __syncthreads();
    }
  }
#pragma unroll
  for (int i = 0; i < 4; i++) {
    int m = s1t * 128 + wm * 64 + i * 16 + ((l >> 4) << 2);
#pragma unroll
    for (int j = 0; j < 4; j++) {
      int n = ht * 128 + wn * 64 + j * 16 + (l & 15);
#pragma unroll
      for (int r = 0; r < 4; r++)
        out[(long)(b * SS + m + r) * HH + n] = 0.5f * acc[i][j][r];
    }
  }
}

// ---------------------------------------------------------------------------
extern "C" void kernel_launch(void* const* d_in, const int* in_sizes, int n_in,
                              void* d_out, int out_size, void* d_ws, size_t ws_size,
                              hipStream_t stream)
{
  const size_t SZ_W = (size_t)HH * HH * 2;           //  2 MB
  const size_t SZ_Q = (size_t)5 * BB * SS * HH * 2;  // 84 MB
  const size_t SZ_V = (size_t)5 * BB * SS * SS * 2;  // 21 MB
  const size_t SZ_O = (size_t)5 * BB * SS * HH * 2;  // 84 MB
  const size_t NEED = SZ_W + SZ_Q + SZ_V + SZ_O;     // 191 MB (proven available r4)
  if (ws_size < NEED) {
    canary<<<1, 1, 0, stream>>>((float*)d_out, (float)(ws_size >> 20));
    return;
  }
  char* ws = (char*)d_ws;
  __bf16* Wt  = (__bf16*)ws;
  __bf16* Qb  = (__bf16*)(ws + SZ_W);
  __bf16* Vb  = (__bf16*)(ws + SZ_W + SZ_Q);
  __bf16* Obf = (__bf16*)(ws + SZ_W + SZ_Q + SZ_V);
  const float* o0 = (const float*)d_in[0];
  const float* o1 = (const float*)d_in[1];
  const float* o2 = (const float*)d_in[2];
  const float* o3 = (const float*)d_in[3];
  const float* o4 = (const float*)d_in[4];

  cast_trW<<<256, 256, 0, stream>>>((const float*)d_in[5], Wt);
  cast_all<<<5 * 4096, 256, 0, stream>>>(o0, o1, o2, o3, o4, Obf);
  qgemm_b16<<<dim3(320, 8), 256, 0, stream>>>(Obf, Wt, Qb);
  gram_b16<<<2048, 256, 0, stream>>>(Qb, Obf, Vb);
  pvgemm<<<512, 256, 0, stream>>>(Vb, Obf, (float*)d_out);
}

// Round 6
// 329.934 us; speedup vs baseline: 1.2207x; 1.0744x over previous
//
#include <hip/hip_runtime.h>
#include <hip/hip_bf16.h>
#include <stdint.h>

// Problem: b=32, s=256, h=1024, 5 options.
// out = 0.5 * sum_n V_n @ o_n,  V_n = sum_{i!=n} softmax_k(q_i . o_k)_n,  q_i = o_i @ W
// bias is softmax-shift-invariant -> ignored.
// Round 6: gram rebuilt as counted-vmcnt 3-buffer pipeline (T3+T4): one raw
// s_barrier per K-step, vmcnt(5) keeps next-step DMAs in flight across it.
// XOR bank swizzle (pre-swizzled global source + swizzled ds_read). qgemm gets
// XCD/L2 locality remap.

#define BB 32
#define SS 256
#define HH 1024

typedef __attribute__((ext_vector_type(4))) float f32x4;
typedef __attribute__((ext_vector_type(8))) __bf16 bf16x8;
typedef __attribute__((ext_vector_type(4))) __bf16 bf16x4;

__device__ constexpr int PAIR(int i, int n) { return i * 4 + (n > i ? n - 1 : n); }

__device__ __forceinline__ void gload_lds16(const void* g, void* l) {
  __builtin_amdgcn_global_load_lds((const __attribute__((address_space(1))) void*)g,
                                   (__attribute__((address_space(3))) void*)l, 16, 0, 0);
}

__global__ void canary(float* out, float v) { out[0] = v; }

// ---------------------------------------------------------------------------
// fp32 -> bf16 flat cast of the 5 options into Obf[m][b][s][h].
__global__ __launch_bounds__(256) void cast_all(
    const float* p0, const float* p1, const float* p2, const float* p3, const float* p4,
    __bf16* __restrict__ dst)
{
  int m = blockIdx.x >> 12;
  long off = ((long)(blockIdx.x & 4095) * 256 + threadIdx.x) * 8;
  const float* src = m == 0 ? p0 : m == 1 ? p1 : m == 2 ? p2 : m == 3 ? p3 : p4;
  float4 v0 = *(const float4*)(src + off);
  float4 v1 = *(const float4*)(src + off + 4);
  bf16x8 h;
  h[0] = (__bf16)v0.x; h[1] = (__bf16)v0.y; h[2] = (__bf16)v0.z; h[3] = (__bf16)v0.w;
  h[4] = (__bf16)v1.x; h[5] = (__bf16)v1.y; h[6] = (__bf16)v1.z; h[7] = (__bf16)v1.w;
  *(bf16x8*)(dst + (long)m * BB * SS * HH + off) = h;
}

// ---------------------------------------------------------------------------
// W (1024x1024 fp32) -> Wt (bf16, transposed). 64x64 tiles, grid 256.
__global__ __launch_bounds__(256) void cast_trW(const float* __restrict__ src,
                                                __bf16* __restrict__ dstT)
{
  __shared__ __bf16 tile[64][72];
  int ct = blockIdx.x & 15, rt = blockIdx.x >> 4;
  const float* s = src + (long)(rt * 64) * 1024 + ct * 64;
  int t = threadIdx.x;
#pragma unroll
  for (int p = 0; p < 4; p++) {
    int c = t + p * 256;
    int row = c >> 4, c4 = c & 15;
    float4 v = *(const float4*)(s + (long)row * 1024 + c4 * 4);
    bf16x4 h;
    h[0] = (__bf16)v.x; h[1] = (__bf16)v.y; h[2] = (__bf16)v.z; h[3] = (__bf16)v.w;
    *(bf16x4*)&tile[row][c4 * 4] = h;
  }
  __syncthreads();
#pragma unroll
  for (int p = 0; p < 4; p++) {
    int c = t + p * 256;
    int hr = c >> 4, s4 = c & 15;
    bf16x4 h;
    h[0] = tile[s4 * 4 + 0][hr];
    h[1] = tile[s4 * 4 + 1][hr];
    h[2] = tile[s4 * 4 + 2][hr];
    h[3] = tile[s4 * 4 + 3][hr];
    *(bf16x4*)(dstT + (long)(ct * 64 + hr) * 1024 + rt * 64 + s4 * 4) = h;
  }
}

// ---------------------------------------------------------------------------
// qgemm: Q = Obf @ Wt. m97 structure + XCD/L2 locality remap: each XCD owns a
// 40-rt slab; its 8 ct-blocks per rt run back-to-back so the A-tile (256KB)
// stays L2-resident. grid = 2560 x 1.
__global__ __launch_bounds__(256) void qgemm_b16(
    const __bf16* __restrict__ A, const __bf16* __restrict__ Bt, __bf16* __restrict__ C)
{
  __shared__ __align__(16) __bf16 smA[128][32];
  __shared__ __align__(16) __bf16 smB[128][32];
  int lin = blockIdx.x;
  int xcd = lin & 7, idx = lin >> 3;
  int rt = xcd * 40 + (idx >> 3), ct = idx & 7;
  int t = threadIdx.x, l = t & 63, w = t >> 6;
  int wm = w >> 1, wn = w & 1;
  f32x4 acc[4][4] = {};
  for (int k0 = 0; k0 < 1024; k0 += 32) {
#pragma unroll
    for (int p = 0; p < 2; p++) {
      int c = t + p * 256;
      int row = c >> 2, half = c & 3;
      gload_lds16(A + (long)(rt * 128 + row) * 1024 + k0 + half * 8,
                  (char*)smA + ((c >> 6) << 10));
      gload_lds16(Bt + (long)(ct * 128 + row) * 1024 + k0 + half * 8,
                  (char*)smB + ((c >> 6) << 10));
    }
    __syncthreads();
    bf16x8 af[4], bfr[4];
    int sl = l >> 4, lr = l & 15;
#pragma unroll
    for (int i = 0; i < 4; i++) {
      af[i]  = *(const bf16x8*)&smA[wm * 64 + i * 16 + lr][sl * 8];
      bfr[i] = *(const bf16x8*)&smB[wn * 64 + i * 16 + lr][sl * 8];
    }
#pragma unroll
    for (int i = 0; i < 4; i++)
#pragma unroll
      for (int j = 0; j < 4; j++)
        acc[i][j] = __builtin_amdgcn_mfma_f32_16x16x32_bf16(af[i], bfr[j], acc[i][j], 0, 0, 0);
    __syncthreads();
  }
#pragma unroll
  for (int i = 0; i < 4; i++) {
    long mrow = (long)rt * 128 + wm * 64 + i * 16 + ((l >> 4) << 2);
#pragma unroll
    for (int j = 0; j < 4; j++) {
      int n = ct * 128 + wn * 64 + j * 16 + (l & 15);
#pragma unroll
      for (int r = 0; r < 4; r++)
        C[(mrow + r) * 1024 + n] = (__bf16)acc[i][j][r];
    }
  }
}

// ---------------------------------------------------------------------------
// gram: 20 cross-grams + lane-local softmax -> V.
// 4 waves (2x2 patches of 16x16) = 32 s1 x 32 s2 per block.
// 3-buffer counted-vmcnt pipeline: step ks waits vmcnt(5) [stage(ks) done,
// stage(ks+1) stays in flight], raw s_barrier, issues stage(ks+2), computes.
// LDS layout per buffer: 20 groups x 1KB (Q: g=2m+half, O: 10+2m+half),
// rows of 64B with XOR slot swizzle (pre-swizzled on the global source).
__global__ __launch_bounds__(256, 2) void gram_b16(
    const __bf16* __restrict__ Q, const __bf16* __restrict__ O, __bf16* __restrict__ V)
{
  __shared__ __align__(16) char ldsb[3 * 20480];  // 60 KB
  int bid = blockIdx.x;
  int b = bid >> 6, s1t = (bid >> 3) & 7, s2t = bid & 7;
  int t = threadIdx.x, l = t & 63, w = t >> 6;
  int pr = w >> 1, pc = w & 1;
  f32x4 acc[20] = {};

  // --- per-thread staging pointers (5 chunk-groups per thread), k0 = 0 ---
  // group g = 4p + w; g<10 -> Q tile (m=g>>1, half=g&1), else O.
  // lane l covers (row = half*16 + (l>>2), slot_lin = l&3); source slot is
  // pre-swizzled: slog = (l&3) ^ ((l>>3)&3)  [= slot ^ ((row>>1)&3)].
  long qrow0 = (long)b * SS + s1t * 32;
  long orow0 = (long)b * SS + s2t * 32;
  int slog = (l & 3) ^ ((l >> 3) & 3);
  const char* gp0; const char* gp1; const char* gp2; const char* gp3; const char* gp4;
#define GP_INIT(GP, P)                                                                \
  {                                                                                   \
    int g = 4 * (P) + w;                                                              \
    int isQ = g < 10;                                                                 \
    int gg = isQ ? g : g - 10;                                                        \
    long row = (long)(gg >> 1) * (BB * SS) + (isQ ? qrow0 : orow0) + (g & 1) * 16 +   \
               (l >> 2);                                                              \
    GP = (const char*)((isQ ? Q : O) + row * HH + slog * 8);                          \
  }
  GP_INIT(gp0, 0) GP_INIT(gp1, 1) GP_INIT(gp2, 2) GP_INIT(gp3, 3) GP_INIT(gp4, 4)
#undef GP_INIT
  int g0 = w, g1 = 4 + w, g2 = 8 + w, g3 = 12 + w, g4 = 16 + w;

#define STAGE(BB_)                                                      \
  {                                                                     \
    char* base = ldsb + (BB_) * 20480;                                  \
    gload_lds16(gp0, base + g0 * 1024); gp0 += 64;                      \
    gload_lds16(gp1, base + g1 * 1024); gp1 += 64;                      \
    gload_lds16(gp2, base + g2 * 1024); gp2 += 64;                      \
    gload_lds16(gp3, base + g3 * 1024); gp3 += 64;                      \
    gload_lds16(gp4, base + g4 * 1024); gp4 += 64;                      \
  }

  // per-thread LDS read offsets (same XOR swizzle as the source)
  int lr = l & 15, sl = l >> 4;
  int swz = (sl ^ ((lr >> 1) & 3)) * 16;
  int qoff = (pr * 16 + lr) * 64 + swz;          // within Q group block
  int ooff = 10240 + (pc * 16 + lr) * 64 + swz;  // within O group block

#define COMPUTE(BB_)                                                                   \
  {                                                                                    \
    const char* base = ldsb + (BB_) * 20480;                                           \
    bf16x8 qf[5], of[5];                                                               \
    _Pragma("unroll") for (int m = 0; m < 5; m++) {                                    \
      qf[m] = *(const bf16x8*)(base + m * 2048 + qoff);                                \
      of[m] = *(const bf16x8*)(base + m * 2048 + ooff);                                \
    }                                                                                  \
    __builtin_amdgcn_s_setprio(1);                                                     \
    _Pragma("unroll") for (int i = 0; i < 5; i++) {                                    \
      _Pragma("unroll") for (int n = 0; n < 5; n++) {                                  \
        if (n != i)                                                                    \
          acc[PAIR(i, n)] =                                                            \
              __builtin_amdgcn_mfma_f32_16x16x32_bf16(qf[i], of[n], acc[PAIR(i, n)],   \
                                                      0, 0, 0);                        \
      }                                                                                \
    }                                                                                  \
    __builtin_amdgcn_s_setprio(0);                                                     \
  }

#define STEP(CUR, STG)                                          \
  asm volatile("s_waitcnt vmcnt(5)" ::: "memory");              \
  __builtin_amdgcn_s_barrier();                                 \
  STAGE(STG);                                                   \
  COMPUTE(CUR);

  STAGE(0)  // stage(0) -> buf0
  STAGE(1)  // stage(1) -> buf1 ; vmcnt now 10 outstanding
  for (int it = 0; it < 10; it++) {  // ks = 3it .. 3it+2, covers 0..29
    STEP(0, 2)
    STEP(1, 0)
    STEP(2, 1)
  }
  // ks = 30: outstanding = stage(30)+stage(31) = 10 -> wait 5, no stage
  asm volatile("s_waitcnt vmcnt(5)" ::: "memory");
  __builtin_amdgcn_s_barrier();
  COMPUTE(0)
  // ks = 31: outstanding = stage(31) = 5 -> full drain, no stage
  asm volatile("s_waitcnt vmcnt(0)" ::: "memory");
  __builtin_amdgcn_s_barrier();
  COMPUTE(1)
#undef STEP
#undef COMPUTE
#undef STAGE

  int s1g = s1t * 32 + pr * 16 + ((l >> 4) << 2);
  int s2g = s2t * 32 + pc * 16 + (l & 15);
#pragma unroll
  for (int r = 0; r < 4; r++) {
    float vacc[5] = {0.f, 0.f, 0.f, 0.f, 0.f};
#pragma unroll
    for (int i = 0; i < 5; i++) {
      float gg[5];
      float mx = -3.0e38f;
#pragma unroll
      for (int n = 0; n < 5; n++)
        if (n != i) { gg[n] = acc[PAIR(i, n)][r]; mx = fmaxf(mx, gg[n]); }
      float ee[5], ssum = 0.f;
#pragma unroll
      for (int n = 0; n < 5; n++)
        if (n != i) { ee[n] = __expf(gg[n] - mx); ssum += ee[n]; }
      float inv = 1.0f / ssum;
#pragma unroll
      for (int n = 0; n < 5; n++)
        if (n != i) vacc[n] += ee[n] * inv;
    }
#pragma unroll
    for (int n = 0; n < 5; n++)
      V[((long)(n * 32 + b) * 256 + s1g + r) * 256 + s2g] = (__bf16)vacc[n];
  }
}

// ---------------------------------------------------------------------------
// out = 0.5 * sum_n V_n @ o_n (per batch). A: V rows (bf16, s2-contig).
// B: Obf bf16 (s2 x h), transposed in LDS via 4x4 register sub-blocks.
__global__ __launch_bounds__(256) void pvgemm(
    const __bf16* __restrict__ Vb, const __bf16* __restrict__ Obf, float* __restrict__ out)
{
  __shared__ __bf16 smA[128][40];
  __shared__ __bf16 smB[128][40];
  int bid = blockIdx.x;
  int b = bid >> 4, s1t = (bid >> 3) & 1, ht = bid & 7;
  int t = threadIdx.x, l = t & 63, w = t >> 6;
  int wm = w >> 1, wn = w & 1;
  f32x4 acc[4][4] = {};
#pragma unroll
  for (int n = 0; n < 5; n++) {
    const __bf16* On = Obf + (long)n * BB * SS * HH;
    for (int st2 = 0; st2 < 8; st2++) {
      int s20 = st2 * 32;
#pragma unroll
      for (int p = 0; p < 2; p++) {
        int c = t + p * 256;
        int row = c >> 2, sl = c & 3;
        *(bf16x8*)&smA[row][sl * 8] =
            *(const bf16x8*)(Vb + (long)(n * BB + b) * SS * SS + (long)(s1t * 128 + row) * SS +
                             s20 + sl * 8);
      }
      {
        int h4 = (t & 31) * 4, s2q = (t >> 5) * 4;
        const __bf16* src = On + ((long)b * 256 + s20 + s2q) * 1024 + ht * 128 + h4;
        bf16x4 v0 = *(const bf16x4*)(src);
        bf16x4 v1 = *(const bf16x4*)(src + 1024);
        bf16x4 v2 = *(const bf16x4*)(src + 2048);
        bf16x4 v3 = *(const bf16x4*)(src + 3072);
        bf16x4 c0, c1, c2, c3;
        c0[0] = v0[0]; c0[1] = v1[0]; c0[2] = v2[0]; c0[3] = v3[0];
        c1[0] = v0[1]; c1[1] = v1[1]; c1[2] = v2[1]; c1[3] = v3[1];
        c2[0] = v0[2]; c2[1] = v1[2]; c2[2] = v2[2]; c2[3] = v3[2];
        c3[0] = v0[3]; c3[1] = v1[3]; c3[2] = v2[3]; c3[3] = v3[3];
        *(bf16x4*)&smB[h4 + 0][s2q] = c0;
        *(bf16x4*)&smB[h4 + 1][s2q] = c1;
        *(bf16x4*)&smB[h4 + 2][s2q] = c2;
        *(bf16x4*)&smB[h4 + 3][s2q] = c3;
      }
      __syncthreads();
      bf16x8 af[4], bfr[4];
      int sl = l >> 4, lr = l & 15;
#pragma unroll
      for (int i = 0; i < 4; i++) {
        af[i]  = *(const bf16x8*)&smA[wm * 64 + i * 16 + lr][sl * 8];
        bfr[i] = *(const bf16x8*)&smB[wn * 64 + i * 16 + lr][sl * 8];
      }
#pragma unroll
      for (int i = 0; i < 4; i++)
#pragma unroll
        for (int j = 0; j < 4; j++)
          acc[i][j] = __builtin_amdgcn_mfma_f32_16x16x32_bf16(af[i], bfr[j], acc[i][j], 0, 0, 0);
      __syncthreads();
    }
  }
#pragma unroll
  for (int i = 0; i < 4; i++) {
    int m = s1t * 128 + wm * 64 + i * 16 + ((l >> 4) << 2);
#pragma unroll
    for (int j = 0; j < 4; j++) {
      int n = ht * 128 + wn * 64 + j * 16 + (l & 15);
#pragma unroll
      for (int r = 0; r < 4; r++)
        out[(long)(b * SS + m + r) * HH + n] = 0.5f * acc[i][j][r];
    }
  }
}

// ---------------------------------------------------------------------------
extern "C" void kernel_launch(void* const* d_in, const int* in_sizes, int n_in,
                              void* d_out, int out_size, void* d_ws, size_t ws_size,
                              hipStream_t stream)
{
  const size_t SZ_W = (size_t)HH * HH * 2;           //  2 MB
  const size_t SZ_Q = (size_t)5 * BB * SS * HH * 2;  // 84 MB
  const size_t SZ_V = (size_t)5 * BB * SS * SS * 2;  // 21 MB
  const size_t SZ_O = (size_t)5 * BB * SS * HH * 2;  // 84 MB
  const size_t NEED = SZ_W + SZ_Q + SZ_V + SZ_O;     // 191 MB (proven available r4)
  if (ws_size < NEED) {
    canary<<<1, 1, 0, stream>>>((float*)d_out, (float)(ws_size >> 20));
    return;
  }
  char* ws = (char*)d_ws;
  __bf16* Wt  = (__bf16*)ws;
  __bf16* Qb  = (__bf16*)(ws + SZ_W);
  __bf16* Vb  = (__bf16*)(ws + SZ_W + SZ_Q);
  __bf16* Obf = (__bf16*)(ws + SZ_W + SZ_Q + SZ_V);
  const float* o0 = (const float*)d_in[0];
  const float* o1 = (const float*)d_in[1];
  const float* o2 = (const float*)d_in[2];
  const float* o3 = (const float*)d_in[3];
  const float* o4 = (const float*)d_in[4];

  cast_trW<<<256, 256, 0, stream>>>((const float*)d_in[5], Wt);
  cast_all<<<5 * 4096, 256, 0, stream>>>(o0, o1, o2, o3, o4, Obf);
  qgemm_b16<<<2560, 256, 0, stream>>>(Obf, Wt, Qb);
  gram_b16<<<2048, 256, 0, stream>>>(Qb, Obf, Vb);
  pvgemm<<<512, 256, 0, stream>>>(Vb, Obf, (float*)d_out);
}

// Round 7
// 303.137 us; speedup vs baseline: 1.3286x; 1.0884x over previous
//
#include <hip/hip_runtime.h>
#include <hip/hip_bf16.h>
#include <stdint.h>

// Problem: b=32, s=256, h=1024, 5 options.
// out = 0.5 * sum_n V_n @ o_n,  V_n = sum_{i!=n} softmax_k(q_i . o_k)_n,  q_i = o_i @ W
// bias is softmax-shift-invariant -> ignored.
// Round 7: gram gets bijective XCD-chunked block swizzle (T1): XCD x owns
// batches 4x..4x+3, s1t-major within batch -> Q-slab + batch-O become
// L2-resident, DMA latency 900->~250cyc, inside the depth-2 vmcnt lookahead.
// Single-variable change vs round 6.

#define BB 32
#define SS 256
#define HH 1024

typedef __attribute__((ext_vector_type(4))) float f32x4;
typedef __attribute__((ext_vector_type(8))) __bf16 bf16x8;
typedef __attribute__((ext_vector_type(4))) __bf16 bf16x4;

__device__ constexpr int PAIR(int i, int n) { return i * 4 + (n > i ? n - 1 : n); }

__device__ __forceinline__ void gload_lds16(const void* g, void* l) {
  __builtin_amdgcn_global_load_lds((const __attribute__((address_space(1))) void*)g,
                                   (__attribute__((address_space(3))) void*)l, 16, 0, 0);
}

__global__ void canary(float* out, float v) { out[0] = v; }

// ---------------------------------------------------------------------------
// fp32 -> bf16 flat cast of the 5 options into Obf[m][b][s][h].
__global__ __launch_bounds__(256) void cast_all(
    const float* p0, const float* p1, const float* p2, const float* p3, const float* p4,
    __bf16* __restrict__ dst)
{
  int m = blockIdx.x >> 12;
  long off = ((long)(blockIdx.x & 4095) * 256 + threadIdx.x) * 8;
  const float* src = m == 0 ? p0 : m == 1 ? p1 : m == 2 ? p2 : m == 3 ? p3 : p4;
  float4 v0 = *(const float4*)(src + off);
  float4 v1 = *(const float4*)(src + off + 4);
  bf16x8 h;
  h[0] = (__bf16)v0.x; h[1] = (__bf16)v0.y; h[2] = (__bf16)v0.z; h[3] = (__bf16)v0.w;
  h[4] = (__bf16)v1.x; h[5] = (__bf16)v1.y; h[6] = (__bf16)v1.z; h[7] = (__bf16)v1.w;
  *(bf16x8*)(dst + (long)m * BB * SS * HH + off) = h;
}

// ---------------------------------------------------------------------------
// W (1024x1024 fp32) -> Wt (bf16, transposed). 64x64 tiles, grid 256.
__global__ __launch_bounds__(256) void cast_trW(const float* __restrict__ src,
                                                __bf16* __restrict__ dstT)
{
  __shared__ __bf16 tile[64][72];
  int ct = blockIdx.x & 15, rt = blockIdx.x >> 4;
  const float* s = src + (long)(rt * 64) * 1024 + ct * 64;
  int t = threadIdx.x;
#pragma unroll
  for (int p = 0; p < 4; p++) {
    int c = t + p * 256;
    int row = c >> 4, c4 = c & 15;
    float4 v = *(const float4*)(s + (long)row * 1024 + c4 * 4);
    bf16x4 h;
    h[0] = (__bf16)v.x; h[1] = (__bf16)v.y; h[2] = (__bf16)v.z; h[3] = (__bf16)v.w;
    *(bf16x4*)&tile[row][c4 * 4] = h;
  }
  __syncthreads();
#pragma unroll
  for (int p = 0; p < 4; p++) {
    int c = t + p * 256;
    int hr = c >> 4, s4 = c & 15;
    bf16x4 h;
    h[0] = tile[s4 * 4 + 0][hr];
    h[1] = tile[s4 * 4 + 1][hr];
    h[2] = tile[s4 * 4 + 2][hr];
    h[3] = tile[s4 * 4 + 3][hr];
    *(bf16x4*)(dstT + (long)(ct * 64 + hr) * 1024 + rt * 64 + s4 * 4) = h;
  }
}

// ---------------------------------------------------------------------------
// qgemm: Q = Obf @ Wt. m97 structure + XCD/L2 locality remap. grid = 2560.
__global__ __launch_bounds__(256) void qgemm_b16(
    const __bf16* __restrict__ A, const __bf16* __restrict__ Bt, __bf16* __restrict__ C)
{
  __shared__ __align__(16) __bf16 smA[128][32];
  __shared__ __align__(16) __bf16 smB[128][32];
  int lin = blockIdx.x;
  int xcd = lin & 7, idx = lin >> 3;
  int rt = xcd * 40 + (idx >> 3), ct = idx & 7;
  int t = threadIdx.x, l = t & 63, w = t >> 6;
  int wm = w >> 1, wn = w & 1;
  f32x4 acc[4][4] = {};
  for (int k0 = 0; k0 < 1024; k0 += 32) {
#pragma unroll
    for (int p = 0; p < 2; p++) {
      int c = t + p * 256;
      int row = c >> 2, half = c & 3;
      gload_lds16(A + (long)(rt * 128 + row) * 1024 + k0 + half * 8,
                  (char*)smA + ((c >> 6) << 10));
      gload_lds16(Bt + (long)(ct * 128 + row) * 1024 + k0 + half * 8,
                  (char*)smB + ((c >> 6) << 10));
    }
    __syncthreads();
    bf16x8 af[4], bfr[4];
    int sl = l >> 4, lr = l & 15;
#pragma unroll
    for (int i = 0; i < 4; i++) {
      af[i]  = *(const bf16x8*)&smA[wm * 64 + i * 16 + lr][sl * 8];
      bfr[i] = *(const bf16x8*)&smB[wn * 64 + i * 16 + lr][sl * 8];
    }
#pragma unroll
    for (int i = 0; i < 4; i++)
#pragma unroll
      for (int j = 0; j < 4; j++)
        acc[i][j] = __builtin_amdgcn_mfma_f32_16x16x32_bf16(af[i], bfr[j], acc[i][j], 0, 0, 0);
    __syncthreads();
  }
#pragma unroll
  for (int i = 0; i < 4; i++) {
    long mrow = (long)rt * 128 + wm * 64 + i * 16 + ((l >> 4) << 2);
#pragma unroll
    for (int j = 0; j < 4; j++) {
      int n = ct * 128 + wn * 64 + j * 16 + (l & 15);
#pragma unroll
      for (int r = 0; r < 4; r++)
        C[(mrow + r) * 1024 + n] = (__bf16)acc[i][j][r];
    }
  }
}

// ---------------------------------------------------------------------------
// gram: 20 cross-grams + lane-local softmax -> V.
// 4 waves (2x2 patches of 16x16) = 32 s1 x 32 s2 per block.
// 3-buffer counted-vmcnt pipeline (round 6) + XCD-chunked swizzle (round 7):
// XCD x owns batches 4x..4x+3; within a batch s1t-major so the 8 concurrent
// blocks share one Q-slab and keep the batch O (2.6MB) L2-resident.
__global__ __launch_bounds__(256, 2) void gram_b16(
    const __bf16* __restrict__ Q, const __bf16* __restrict__ O, __bf16* __restrict__ V)
{
  __shared__ __align__(16) char ldsb[3 * 20480];  // 60 KB
  int bid = blockIdx.x;
  int xcd = bid & 7, idx = bid >> 3;          // 2048 = 8 XCD x 256 (bijective)
  int b = xcd * 4 + (idx >> 6);               // 4 batches per XCD
  int rem = idx & 63;
  int s1t = rem >> 3, s2t = rem & 7;          // s1t-major within batch
  int t = threadIdx.x, l = t & 63, w = t >> 6;
  int pr = w >> 1, pc = w & 1;
  f32x4 acc[20] = {};

  long qrow0 = (long)b * SS + s1t * 32;
  long orow0 = (long)b * SS + s2t * 32;
  int slog = (l & 3) ^ ((l >> 3) & 3);
  const char* gp0; const char* gp1; const char* gp2; const char* gp3; const char* gp4;
#define GP_INIT(GP, P)                                                                \
  {                                                                                   \
    int g = 4 * (P) + w;                                                              \
    int isQ = g < 10;                                                                 \
    int gg = isQ ? g : g - 10;                                                        \
    long row = (long)(gg >> 1) * (BB * SS) + (isQ ? qrow0 : orow0) + (g & 1) * 16 +   \
               (l >> 2);                                                              \
    GP = (const char*)((isQ ? Q : O) + row * HH + slog * 8);                          \
  }
  GP_INIT(gp0, 0) GP_INIT(gp1, 1) GP_INIT(gp2, 2) GP_INIT(gp3, 3) GP_INIT(gp4, 4)
#undef GP_INIT
  int g0 = w, g1 = 4 + w, g2 = 8 + w, g3 = 12 + w, g4 = 16 + w;

#define STAGE(BB_)                                                      \
  {                                                                     \
    char* base = ldsb + (BB_) * 20480;                                  \
    gload_lds16(gp0, base + g0 * 1024); gp0 += 64;                      \
    gload_lds16(gp1, base + g1 * 1024); gp1 += 64;                      \
    gload_lds16(gp2, base + g2 * 1024); gp2 += 64;                      \
    gload_lds16(gp3, base + g3 * 1024); gp3 += 64;                      \
    gload_lds16(gp4, base + g4 * 1024); gp4 += 64;                      \
  }

  int lr = l & 15, sl = l >> 4;
  int swz = (sl ^ ((lr >> 1) & 3)) * 16;
  int qoff = (pr * 16 + lr) * 64 + swz;
  int ooff = 10240 + (pc * 16 + lr) * 64 + swz;

#define COMPUTE(BB_)                                                                   \
  {                                                                                    \
    const char* base = ldsb + (BB_) * 20480;                                           \
    bf16x8 qf[5], of[5];                                                               \
    _Pragma("unroll") for (int m = 0; m < 5; m++) {                                    \
      qf[m] = *(const bf16x8*)(base + m * 2048 + qoff);                                \
      of[m] = *(const bf16x8*)(base + m * 2048 + ooff);                                \
    }                                                                                  \
    __builtin_amdgcn_s_setprio(1);                                                     \
    _Pragma("unroll") for (int i = 0; i < 5; i++) {                                    \
      _Pragma("unroll") for (int n = 0; n < 5; n++) {                                  \
        if (n != i)                                                                    \
          acc[PAIR(i, n)] =                                                            \
              __builtin_amdgcn_mfma_f32_16x16x32_bf16(qf[i], of[n], acc[PAIR(i, n)],   \
                                                      0, 0, 0);                        \
      }                                                                                \
    }                                                                                  \
    __builtin_amdgcn_s_setprio(0);                                                     \
  }

#define STEP(CUR, STG)                                          \
  asm volatile("s_waitcnt vmcnt(5)" ::: "memory");              \
  __builtin_amdgcn_s_barrier();                                 \
  STAGE(STG);                                                   \
  COMPUTE(CUR);

  STAGE(0)
  STAGE(1)
  for (int it = 0; it < 10; it++) {
    STEP(0, 2)
    STEP(1, 0)
    STEP(2, 1)
  }
  asm volatile("s_waitcnt vmcnt(5)" ::: "memory");
  __builtin_amdgcn_s_barrier();
  COMPUTE(0)
  asm volatile("s_waitcnt vmcnt(0)" ::: "memory");
  __builtin_amdgcn_s_barrier();
  COMPUTE(1)
#undef STEP
#undef COMPUTE
#undef STAGE

  int s1g = s1t * 32 + pr * 16 + ((l >> 4) << 2);
  int s2g = s2t * 32 + pc * 16 + (l & 15);
#pragma unroll
  for (int r = 0; r < 4; r++) {
    float vacc[5] = {0.f, 0.f, 0.f, 0.f, 0.f};
#pragma unroll
    for (int i = 0; i < 5; i++) {
      float gg[5];
      float mx = -3.0e38f;
#pragma unroll
      for (int n = 0; n < 5; n++)
        if (n != i) { gg[n] = acc[PAIR(i, n)][r]; mx = fmaxf(mx, gg[n]); }
      float ee[5], ssum = 0.f;
#pragma unroll
      for (int n = 0; n < 5; n++)
        if (n != i) { ee[n] = __expf(gg[n] - mx); ssum += ee[n]; }
      float inv = 1.0f / ssum;
#pragma unroll
      for (int n = 0; n < 5; n++)
        if (n != i) vacc[n] += ee[n] * inv;
    }
#pragma unroll
    for (int n = 0; n < 5; n++)
      V[((long)(n * 32 + b) * 256 + s1g + r) * 256 + s2g] = (__bf16)vacc[n];
  }
}

// ---------------------------------------------------------------------------
// out = 0.5 * sum_n V_n @ o_n (per batch). A: V rows (bf16, s2-contig).
// B: Obf bf16 (s2 x h), transposed in LDS via 4x4 register sub-blocks.
__global__ __launch_bounds__(256) void pvgemm(
    const __bf16* __restrict__ Vb, const __bf16* __restrict__ Obf, float* __restrict__ out)
{
  __shared__ __bf16 smA[128][40];
  __shared__ __bf16 smB[128][40];
  int bid = blockIdx.x;
  int b = bid >> 4, s1t = (bid >> 3) & 1, ht = bid & 7;
  int t = threadIdx.x, l = t & 63, w = t >> 6;
  int wm = w >> 1, wn = w & 1;
  f32x4 acc[4][4] = {};
#pragma unroll
  for (int n = 0; n < 5; n++) {
    const __bf16* On = Obf + (long)n * BB * SS * HH;
    for (int st2 = 0; st2 < 8; st2++) {
      int s20 = st2 * 32;
#pragma unroll
      for (int p = 0; p < 2; p++) {
        int c = t + p * 256;
        int row = c >> 2, sl = c & 3;
        *(bf16x8*)&smA[row][sl * 8] =
            *(const bf16x8*)(Vb + (long)(n * BB + b) * SS * SS + (long)(s1t * 128 + row) * SS +
                             s20 + sl * 8);
      }
      {
        int h4 = (t & 31) * 4, s2q = (t >> 5) * 4;
        const __bf16* src = On + ((long)b * 256 + s20 + s2q) * 1024 + ht * 128 + h4;
        bf16x4 v0 = *(const bf16x4*)(src);
        bf16x4 v1 = *(const bf16x4*)(src + 1024);
        bf16x4 v2 = *(const bf16x4*)(src + 2048);
        bf16x4 v3 = *(const bf16x4*)(src + 3072);
        bf16x4 c0, c1, c2, c3;
        c0[0] = v0[0]; c0[1] = v1[0]; c0[2] = v2[0]; c0[3] = v3[0];
        c1[0] = v0[1]; c1[1] = v1[1]; c1[2] = v2[1]; c1[3] = v3[1];
        c2[0] = v0[2]; c2[1] = v1[2]; c2[2] = v2[2]; c2[3] = v3[2];
        c3[0] = v0[3]; c3[1] = v1[3]; c3[2] = v2[3]; c3[3] = v3[3];
        *(bf16x4*)&smB[h4 + 0][s2q] = c0;
        *(bf16x4*)&smB[h4 + 1][s2q] = c1;
        *(bf16x4*)&smB[h4 + 2][s2q] = c2;
        *(bf16x4*)&smB[h4 + 3][s2q] = c3;
      }
      __syncthreads();
      bf16x8 af[4], bfr[4];
      int sl = l >> 4, lr = l & 15;
#pragma unroll
      for (int i = 0; i < 4; i++) {
        af[i]  = *(const bf16x8*)&smA[wm * 64 + i * 16 + lr][sl * 8];
        bfr[i] = *(const bf16x8*)&smB[wn * 64 + i * 16 + lr][sl * 8];
      }
#pragma unroll
      for (int i = 0; i < 4; i++)
#pragma unroll
        for (int j = 0; j < 4; j++)
          acc[i][j] = __builtin_amdgcn_mfma_f32_16x16x32_bf16(af[i], bfr[j], acc[i][j], 0, 0, 0);
      __syncthreads();
    }
  }
#pragma unroll
  for (int i = 0; i < 4; i++) {
    int m = s1t * 128 + wm * 64 + i * 16 + ((l >> 4) << 2);
#pragma unroll
    for (int j = 0; j < 4; j++) {
      int n = ht * 128 + wn * 64 + j * 16 + (l & 15);
#pragma unroll
      for (int r = 0; r < 4; r++)
        out[(long)(b * SS + m + r) * HH + n] = 0.5f * acc[i][j][r];
    }
  }
}

// ---------------------------------------------------------------------------
extern "C" void kernel_launch(void* const* d_in, const int* in_sizes, int n_in,
                              void* d_out, int out_size, void* d_ws, size_t ws_size,
                              hipStream_t stream)
{
  const size_t SZ_W = (size_t)HH * HH * 2;           //  2 MB
  const size_t SZ_Q = (size_t)5 * BB * SS * HH * 2;  // 84 MB
  const size_t SZ_V = (size_t)5 * BB * SS * SS * 2;  // 21 MB
  const size_t SZ_O = (size_t)5 * BB * SS * HH * 2;  // 84 MB
  const size_t NEED = SZ_W + SZ_Q + SZ_V + SZ_O;     // 191 MB (proven available r4)
  if (ws_size < NEED) {
    canary<<<1, 1, 0, stream>>>((float*)d_out, (float)(ws_size >> 20));
    return;
  }
  char* ws = (char*)d_ws;
  __bf16* Wt  = (__bf16*)ws;
  __bf16* Qb  = (__bf16*)(ws + SZ_W);
  __bf16* Vb  = (__bf16*)(ws + SZ_W + SZ_Q);
  __bf16* Obf = (__bf16*)(ws + SZ_W + SZ_Q + SZ_V);
  const float* o0 = (const float*)d_in[0];
  const float* o1 = (const float*)d_in[1];
  const float* o2 = (const float*)d_in[2];
  const float* o3 = (const float*)d_in[3];
  const float* o4 = (const float*)d_in[4];

  cast_trW<<<256, 256, 0, stream>>>((const float*)d_in[5], Wt);
  cast_all<<<5 * 4096, 256, 0, stream>>>(o0, o1, o2, o3, o4, Obf);
  qgemm_b16<<<2560, 256, 0, stream>>>(Obf, Wt, Qb);
  gram_b16<<<2048, 256, 0, stream>>>(Qb, Obf, Vb);
  pvgemm<<<512, 256, 0, stream>>>(Vb, Obf, (float*)d_out);
}

// Round 8
// 294.902 us; speedup vs baseline: 1.3657x; 1.0279x over previous
//
#include <hip/hip_runtime.h>
#include <hip/hip_bf16.h>
#include <stdint.h>

// Problem: b=32, s=256, h=1024, 5 options.
// out = 0.5 * sum_n V_n @ o_n,  V_n = sum_{i!=n} softmax_k(q_i . o_k)_n,  q_i = o_i @ W
// bias is softmax-shift-invariant -> ignored.
// Round 8: qgemm rebuilt with gram's proven recipe: 3-buffer counted-vmcnt
// pipeline (vmcnt(4), one raw s_barrier/step), both-sides XOR bank swizzle,
// setprio around MFMA, per-thread advancing stage pointers. Single change.

#define BB 32
#define SS 256
#define HH 1024

typedef __attribute__((ext_vector_type(4))) float f32x4;
typedef __attribute__((ext_vector_type(8))) __bf16 bf16x8;
typedef __attribute__((ext_vector_type(4))) __bf16 bf16x4;

__device__ constexpr int PAIR(int i, int n) { return i * 4 + (n > i ? n - 1 : n); }

__device__ __forceinline__ void gload_lds16(const void* g, void* l) {
  __builtin_amdgcn_global_load_lds((const __attribute__((address_space(1))) void*)g,
                                   (__attribute__((address_space(3))) void*)l, 16, 0, 0);
}

__global__ void canary(float* out, float v) { out[0] = v; }

// ---------------------------------------------------------------------------
// fp32 -> bf16 flat cast of the 5 options into Obf[m][b][s][h].
__global__ __launch_bounds__(256) void cast_all(
    const float* p0, const float* p1, const float* p2, const float* p3, const float* p4,
    __bf16* __restrict__ dst)
{
  int m = blockIdx.x >> 12;
  long off = ((long)(blockIdx.x & 4095) * 256 + threadIdx.x) * 8;
  const float* src = m == 0 ? p0 : m == 1 ? p1 : m == 2 ? p2 : m == 3 ? p3 : p4;
  float4 v0 = *(const float4*)(src + off);
  float4 v1 = *(const float4*)(src + off + 4);
  bf16x8 h;
  h[0] = (__bf16)v0.x; h[1] = (__bf16)v0.y; h[2] = (__bf16)v0.z; h[3] = (__bf16)v0.w;
  h[4] = (__bf16)v1.x; h[5] = (__bf16)v1.y; h[6] = (__bf16)v1.z; h[7] = (__bf16)v1.w;
  *(bf16x8*)(dst + (long)m * BB * SS * HH + off) = h;
}

// ---------------------------------------------------------------------------
// W (1024x1024 fp32) -> Wt (bf16, transposed). 64x64 tiles, grid 256.
__global__ __launch_bounds__(256) void cast_trW(const float* __restrict__ src,
                                                __bf16* __restrict__ dstT)
{
  __shared__ __bf16 tile[64][72];
  int ct = blockIdx.x & 15, rt = blockIdx.x >> 4;
  const float* s = src + (long)(rt * 64) * 1024 + ct * 64;
  int t = threadIdx.x;
#pragma unroll
  for (int p = 0; p < 4; p++) {
    int c = t + p * 256;
    int row = c >> 4, c4 = c & 15;
    float4 v = *(const float4*)(s + (long)row * 1024 + c4 * 4);
    bf16x4 h;
    h[0] = (__bf16)v.x; h[1] = (__bf16)v.y; h[2] = (__bf16)v.z; h[3] = (__bf16)v.w;
    *(bf16x4*)&tile[row][c4 * 4] = h;
  }
  __syncthreads();
#pragma unroll
  for (int p = 0; p < 4; p++) {
    int c = t + p * 256;
    int hr = c >> 4, s4 = c & 15;
    bf16x4 h;
    h[0] = tile[s4 * 4 + 0][hr];
    h[1] = tile[s4 * 4 + 1][hr];
    h[2] = tile[s4 * 4 + 2][hr];
    h[3] = tile[s4 * 4 + 3][hr];
    *(bf16x4*)(dstT + (long)(ct * 64 + hr) * 1024 + rt * 64 + s4 * 4) = h;
  }
}

// ---------------------------------------------------------------------------
// qgemm: Q = Obf @ Wt. 128x128 tile, BK=32, XCD/L2 remap (grid 2560),
// 3-buffer counted-vmcnt pipeline + XOR swizzle (both sides) + setprio.
__global__ __launch_bounds__(256, 3) void qgemm_b16(
    const __bf16* __restrict__ A, const __bf16* __restrict__ Bt, __bf16* __restrict__ C)
{
  __shared__ __align__(16) char ldsb[3 * 16384];  // 48 KB: per buf A[8K] B[8K]
  int lin = blockIdx.x;
  int xcd = lin & 7, idx = lin >> 3;
  int rt = xcd * 40 + (idx >> 3), ct = idx & 7;
  int t = threadIdx.x, l = t & 63, w = t >> 6;
  int wm = w >> 1, wn = w & 1;
  f32x4 acc[4][4] = {};

  // staging: thread t owns chunks c0=t, c1=t+256 (row=c>>2, half=c&3).
  // source half is pre-swizzled: half ^ ((row>>1)&3) = (c&3)^((c>>3)&3).
  const char *gA0, *gA1, *gB0, *gB1;
  {
    int c0 = t, c1 = t + 256;
    int r0 = c0 >> 2, h0 = (c0 & 3) ^ ((c0 >> 3) & 3);
    int r1 = c1 >> 2, h1 = (c1 & 3) ^ ((c1 >> 3) & 3);
    gA0 = (const char*)(A + (long)(rt * 128 + r0) * 1024 + h0 * 8);
    gA1 = (const char*)(A + (long)(rt * 128 + r1) * 1024 + h1 * 8);
    gB0 = (const char*)(Bt + (long)(ct * 128 + r0) * 1024 + h0 * 8);
    gB1 = (const char*)(Bt + (long)(ct * 128 + r1) * 1024 + h1 * 8);
  }
  int dst0 = w * 1024, dst1 = (w + 4) * 1024;  // (c>>6)<<10, wave-uniform

#define STAGE(BUF)                                                \
  {                                                               \
    char* base = ldsb + (BUF) * 16384;                            \
    gload_lds16(gA0, base + dst0); gA0 += 64;                     \
    gload_lds16(gA1, base + dst1); gA1 += 64;                     \
    gload_lds16(gB0, base + 8192 + dst0); gB0 += 64;              \
    gload_lds16(gB1, base + 8192 + dst1); gB1 += 64;              \
  }

  // read offsets: row=sub*16+lr, byte = row*64 + (sl^((lr>>1)&3))*16
  int lr = l & 15, sl = l >> 4;
  int swz = (sl ^ ((lr >> 1) & 3)) * 16;
  int aoff = (wm * 64 + lr) * 64 + swz;
  int boff = 8192 + (wn * 64 + lr) * 64 + swz;

#define COMPUTE(BUF)                                                                   \
  {                                                                                    \
    const char* base = ldsb + (BUF) * 16384;                                           \
    bf16x8 af[4], bfr[4];                                                              \
    _Pragma("unroll") for (int i = 0; i < 4; i++) {                                    \
      af[i]  = *(const bf16x8*)(base + aoff + i * 1024);                               \
      bfr[i] = *(const bf16x8*)(base + boff + i * 1024);                               \
    }                                                                                  \
    __builtin_amdgcn_s_setprio(1);                                                     \
    _Pragma("unroll") for (int i = 0; i < 4; i++)                                      \
      _Pragma("unroll") for (int j = 0; j < 4; j++)                                    \
        acc[i][j] = __builtin_amdgcn_mfma_f32_16x16x32_bf16(af[i], bfr[j],             \
                                                            acc[i][j], 0, 0, 0);       \
    __builtin_amdgcn_s_setprio(0);                                                     \
  }

#define STEP(CUR, STG)                                          \
  asm volatile("s_waitcnt vmcnt(4)" ::: "memory");              \
  __builtin_amdgcn_s_barrier();                                 \
  STAGE(STG);                                                   \
  COMPUTE(CUR);

  STAGE(0)
  STAGE(1)
  for (int it = 0; it < 10; it++) {  // K-steps 0..29
    STEP(0, 2)
    STEP(1, 0)
    STEP(2, 1)
  }
  asm volatile("s_waitcnt vmcnt(4)" ::: "memory");  // K-step 30
  __builtin_amdgcn_s_barrier();
  COMPUTE(0)
  asm volatile("s_waitcnt vmcnt(0)" ::: "memory");  // K-step 31
  __builtin_amdgcn_s_barrier();
  COMPUTE(1)
#undef STEP
#undef COMPUTE
#undef STAGE

#pragma unroll
  for (int i = 0; i < 4; i++) {
    long mrow = (long)rt * 128 + wm * 64 + i * 16 + ((l >> 4) << 2);
#pragma unroll
    for (int j = 0; j < 4; j++) {
      int n = ct * 128 + wn * 64 + j * 16 + (l & 15);
#pragma unroll
      for (int r = 0; r < 4; r++)
        C[(mrow + r) * 1024 + n] = (__bf16)acc[i][j][r];
    }
  }
}

// ---------------------------------------------------------------------------
// gram: 20 cross-grams + lane-local softmax -> V. (round-7 proven)
__global__ __launch_bounds__(256, 2) void gram_b16(
    const __bf16* __restrict__ Q, const __bf16* __restrict__ O, __bf16* __restrict__ V)
{
  __shared__ __align__(16) char ldsb[3 * 20480];  // 60 KB
  int bid = blockIdx.x;
  int xcd = bid & 7, idx = bid >> 3;          // 2048 = 8 XCD x 256 (bijective)
  int b = xcd * 4 + (idx >> 6);               // 4 batches per XCD
  int rem = idx & 63;
  int s1t = rem >> 3, s2t = rem & 7;          // s1t-major within batch
  int t = threadIdx.x, l = t & 63, w = t >> 6;
  int pr = w >> 1, pc = w & 1;
  f32x4 acc[20] = {};

  long qrow0 = (long)b * SS + s1t * 32;
  long orow0 = (long)b * SS + s2t * 32;
  int slog = (l & 3) ^ ((l >> 3) & 3);
  const char* gp0; const char* gp1; const char* gp2; const char* gp3; const char* gp4;
#define GP_INIT(GP, P)                                                                \
  {                                                                                   \
    int g = 4 * (P) + w;                                                              \
    int isQ = g < 10;                                                                 \
    int gg = isQ ? g : g - 10;                                                        \
    long row = (long)(gg >> 1) * (BB * SS) + (isQ ? qrow0 : orow0) + (g & 1) * 16 +   \
               (l >> 2);                                                              \
    GP = (const char*)((isQ ? Q : O) + row * HH + slog * 8);                          \
  }
  GP_INIT(gp0, 0) GP_INIT(gp1, 1) GP_INIT(gp2, 2) GP_INIT(gp3, 3) GP_INIT(gp4, 4)
#undef GP_INIT
  int g0 = w, g1 = 4 + w, g2 = 8 + w, g3 = 12 + w, g4 = 16 + w;

#define STAGE(BB_)                                                      \
  {                                                                     \
    char* base = ldsb + (BB_) * 20480;                                  \
    gload_lds16(gp0, base + g0 * 1024); gp0 += 64;                      \
    gload_lds16(gp1, base + g1 * 1024); gp1 += 64;                      \
    gload_lds16(gp2, base + g2 * 1024); gp2 += 64;                      \
    gload_lds16(gp3, base + g3 * 1024); gp3 += 64;                      \
    gload_lds16(gp4, base + g4 * 1024); gp4 += 64;                      \
  }

  int lr = l & 15, sl = l >> 4;
  int swz = (sl ^ ((lr >> 1) & 3)) * 16;
  int qoff = (pr * 16 + lr) * 64 + swz;
  int ooff = 10240 + (pc * 16 + lr) * 64 + swz;

#define COMPUTE(BB_)                                                                   \
  {                                                                                    \
    const char* base = ldsb + (BB_) * 20480;                                           \
    bf16x8 qf[5], of[5];                                                               \
    _Pragma("unroll") for (int m = 0; m < 5; m++) {                                    \
      qf[m] = *(const bf16x8*)(base + m * 2048 + qoff);                                \
      of[m] = *(const bf16x8*)(base + m * 2048 + ooff);                                \
    }                                                                                  \
    __builtin_amdgcn_s_setprio(1);                                                     \
    _Pragma("unroll") for (int i = 0; i < 5; i++) {                                    \
      _Pragma("unroll") for (int n = 0; n < 5; n++) {                                  \
        if (n != i)                                                                    \
          acc[PAIR(i, n)] =                                                            \
              __builtin_amdgcn_mfma_f32_16x16x32_bf16(qf[i], of[n], acc[PAIR(i, n)],   \
                                                      0, 0, 0);                        \
      }                                                                                \
    }                                                                                  \
    __builtin_amdgcn_s_setprio(0);                                                     \
  }

#define STEP(CUR, STG)                                          \
  asm volatile("s_waitcnt vmcnt(5)" ::: "memory");              \
  __builtin_amdgcn_s_barrier();                                 \
  STAGE(STG);                                                   \
  COMPUTE(CUR);

  STAGE(0)
  STAGE(1)
  for (int it = 0; it < 10; it++) {
    STEP(0, 2)
    STEP(1, 0)
    STEP(2, 1)
  }
  asm volatile("s_waitcnt vmcnt(5)" ::: "memory");
  __builtin_amdgcn_s_barrier();
  COMPUTE(0)
  asm volatile("s_waitcnt vmcnt(0)" ::: "memory");
  __builtin_amdgcn_s_barrier();
  COMPUTE(1)
#undef STEP
#undef COMPUTE
#undef STAGE

  int s1g = s1t * 32 + pr * 16 + ((l >> 4) << 2);
  int s2g = s2t * 32 + pc * 16 + (l & 15);
#pragma unroll
  for (int r = 0; r < 4; r++) {
    float vacc[5] = {0.f, 0.f, 0.f, 0.f, 0.f};
#pragma unroll
    for (int i = 0; i < 5; i++) {
      float gg[5];
      float mx = -3.0e38f;
#pragma unroll
      for (int n = 0; n < 5; n++)
        if (n != i) { gg[n] = acc[PAIR(i, n)][r]; mx = fmaxf(mx, gg[n]); }
      float ee[5], ssum = 0.f;
#pragma unroll
      for (int n = 0; n < 5; n++)
        if (n != i) { ee[n] = __expf(gg[n] - mx); ssum += ee[n]; }
      float inv = 1.0f / ssum;
#pragma unroll
      for (int n = 0; n < 5; n++)
        if (n != i) vacc[n] += ee[n] * inv;
    }
#pragma unroll
    for (int n = 0; n < 5; n++)
      V[((long)(n * 32 + b) * 256 + s1g + r) * 256 + s2g] = (__bf16)vacc[n];
  }
}

// ---------------------------------------------------------------------------
// out = 0.5 * sum_n V_n @ o_n (per batch). A: V rows (bf16, s2-contig).
// B: Obf bf16 (s2 x h), transposed in LDS via 4x4 register sub-blocks.
__global__ __launch_bounds__(256) void pvgemm(
    const __bf16* __restrict__ Vb, const __bf16* __restrict__ Obf, float* __restrict__ out)
{
  __shared__ __bf16 smA[128][40];
  __shared__ __bf16 smB[128][40];
  int bid = blockIdx.x;
  int b = bid >> 4, s1t = (bid >> 3) & 1, ht = bid & 7;
  int t = threadIdx.x, l = t & 63, w = t >> 6;
  int wm = w >> 1, wn = w & 1;
  f32x4 acc[4][4] = {};
#pragma unroll
  for (int n = 0; n < 5; n++) {
    const __bf16* On = Obf + (long)n * BB * SS * HH;
    for (int st2 = 0; st2 < 8; st2++) {
      int s20 = st2 * 32;
#pragma unroll
      for (int p = 0; p < 2; p++) {
        int c = t + p * 256;
        int row = c >> 2, sl = c & 3;
        *(bf16x8*)&smA[row][sl * 8] =
            *(const bf16x8*)(Vb + (long)(n * BB + b) * SS * SS + (long)(s1t * 128 + row) * SS +
                             s20 + sl * 8);
      }
      {
        int h4 = (t & 31) * 4, s2q = (t >> 5) * 4;
        const __bf16* src = On + ((long)b * 256 + s20 + s2q) * 1024 + ht * 128 + h4;
        bf16x4 v0 = *(const bf16x4*)(src);
        bf16x4 v1 = *(const bf16x4*)(src + 1024);
        bf16x4 v2 = *(const bf16x4*)(src + 2048);
        bf16x4 v3 = *(const bf16x4*)(src + 3072);
        bf16x4 c0, c1, c2, c3;
        c0[0] = v0[0]; c0[1] = v1[0]; c0[2] = v2[0]; c0[3] = v3[0];
        c1[0] = v0[1]; c1[1] = v1[1]; c1[2] = v2[1]; c1[3] = v3[1];
        c2[0] = v0[2]; c2[1] = v1[2]; c2[2] = v2[2]; c2[3] = v3[2];
        c3[0] = v0[3]; c3[1] = v1[3]; c3[2] = v2[3]; c3[3] = v3[3];
        *(bf16x4*)&smB[h4 + 0][s2q] = c0;
        *(bf16x4*)&smB[h4 + 1][s2q] = c1;
        *(bf16x4*)&smB[h4 + 2][s2q] = c2;
        *(bf16x4*)&smB[h4 + 3][s2q] = c3;
      }
      __syncthreads();
      bf16x8 af[4], bfr[4];
      int sl = l >> 4, lr = l & 15;
#pragma unroll
      for (int i = 0; i < 4; i++) {
        af[i]  = *(const bf16x8*)&smA[wm * 64 + i * 16 + lr][sl * 8];
        bfr[i] = *(const bf16x8*)&smB[wn * 64 + i * 16 + lr][sl * 8];
      }
#pragma unroll
      for (int i = 0; i < 4; i++)
#pragma unroll
        for (int j = 0; j < 4; j++)
          acc[i][j] = __builtin_amdgcn_mfma_f32_16x16x32_bf16(af[i], bfr[j], acc[i][j], 0, 0, 0);
      __syncthreads();
    }
  }
#pragma unroll
  for (int i = 0; i < 4; i++) {
    int m = s1t * 128 + wm * 64 + i * 16 + ((l >> 4) << 2);
#pragma unroll
    for (int j = 0; j < 4; j++) {
      int n = ht * 128 + wn * 64 + j * 16 + (l & 15);
#pragma unroll
      for (int r = 0; r < 4; r++)
        out[(long)(b * SS + m + r) * HH + n] = 0.5f * acc[i][j][r];
    }
  }
}

// ---------------------------------------------------------------------------
extern "C" void kernel_launch(void* const* d_in, const int* in_sizes, int n_in,
                              void* d_out, int out_size, void* d_ws, size_t ws_size,
                              hipStream_t stream)
{
  const size_t SZ_W = (size_t)HH * HH * 2;           //  2 MB
  const size_t SZ_Q = (size_t)5 * BB * SS * HH * 2;  // 84 MB
  const size_t SZ_V = (size_t)5 * BB * SS * SS * 2;  // 21 MB
  const size_t SZ_O = (size_t)5 * BB * SS * HH * 2;  // 84 MB
  const size_t NEED = SZ_W + SZ_Q + SZ_V + SZ_O;     // 191 MB (proven available r4)
  if (ws_size < NEED) {
    canary<<<1, 1, 0, stream>>>((float*)d_out, (float)(ws_size >> 20));
    return;
  }
  char* ws = (char*)d_ws;
  __bf16* Wt  = (__bf16*)ws;
  __bf16* Qb  = (__bf16*)(ws + SZ_W);
  __bf16* Vb  = (__bf16*)(ws + SZ_W + SZ_Q);
  __bf16* Obf = (__bf16*)(ws + SZ_W + SZ_Q + SZ_V);
  const float* o0 = (const float*)d_in[0];
  const float* o1 = (const float*)d_in[1];
  const float* o2 = (const float*)d_in[2];
  const float* o3 = (const float*)d_in[3];
  const float* o4 = (const float*)d_in[4];

  cast_trW<<<256, 256, 0, stream>>>((const float*)d_in[5], Wt);
  cast_all<<<5 * 4096, 256, 0, stream>>>(o0, o1, o2, o3, o4, Obf);
  qgemm_b16<<<2560, 256, 0, stream>>>(Obf, Wt, Qb);
  gram_b16<<<2048, 256, 0, stream>>>(Qb, Obf, Vb);
  pvgemm<<<512, 256, 0, stream>>>(Vb, Obf, (float*)d_out);
}

// Round 9
// 292.989 us; speedup vs baseline: 1.3746x; 1.0065x over previous
//
#include <hip/hip_runtime.h>
#include <hip/hip_bf16.h>
#include <stdint.h>

// Problem: b=32, s=256, h=1024, 5 options.
// out = 0.5 * sum_n V_n @ o_n,  V_n = sum_{i!=n} softmax_k(q_i . o_k)_n,  q_i = o_i @ W
// bias is softmax-shift-invariant -> ignored.
// Round 9: gram gets register fragment double-buffering: prefetch step t+1's
// frags (10 ds_read) into a 2nd reg set while step t's 20 MFMA run -> LDS and
// MFMA pipes overlap instead of convoying. lgkmcnt(0) after MFMA makes the
// 3-buffer reuse airtight. qgemm/pvgemm/casts unchanged from round 8.

#define BB 32
#define SS 256
#define HH 1024

typedef __attribute__((ext_vector_type(4))) float f32x4;
typedef __attribute__((ext_vector_type(8))) __bf16 bf16x8;
typedef __attribute__((ext_vector_type(4))) __bf16 bf16x4;

__device__ constexpr int PAIR(int i, int n) { return i * 4 + (n > i ? n - 1 : n); }

__device__ __forceinline__ void gload_lds16(const void* g, void* l) {
  __builtin_amdgcn_global_load_lds((const __attribute__((address_space(1))) void*)g,
                                   (__attribute__((address_space(3))) void*)l, 16, 0, 0);
}

__global__ void canary(float* out, float v) { out[0] = v; }

// ---------------------------------------------------------------------------
// fp32 -> bf16 flat cast of the 5 options into Obf[m][b][s][h].
__global__ __launch_bounds__(256) void cast_all(
    const float* p0, const float* p1, const float* p2, const float* p3, const float* p4,
    __bf16* __restrict__ dst)
{
  int m = blockIdx.x >> 12;
  long off = ((long)(blockIdx.x & 4095) * 256 + threadIdx.x) * 8;
  const float* src = m == 0 ? p0 : m == 1 ? p1 : m == 2 ? p2 : m == 3 ? p3 : p4;
  float4 v0 = *(const float4*)(src + off);
  float4 v1 = *(const float4*)(src + off + 4);
  bf16x8 h;
  h[0] = (__bf16)v0.x; h[1] = (__bf16)v0.y; h[2] = (__bf16)v0.z; h[3] = (__bf16)v0.w;
  h[4] = (__bf16)v1.x; h[5] = (__bf16)v1.y; h[6] = (__bf16)v1.z; h[7] = (__bf16)v1.w;
  *(bf16x8*)(dst + (long)m * BB * SS * HH + off) = h;
}

// ---------------------------------------------------------------------------
// W (1024x1024 fp32) -> Wt (bf16, transposed). 64x64 tiles, grid 256.
__global__ __launch_bounds__(256) void cast_trW(const float* __restrict__ src,
                                                __bf16* __restrict__ dstT)
{
  __shared__ __bf16 tile[64][72];
  int ct = blockIdx.x & 15, rt = blockIdx.x >> 4;
  const float* s = src + (long)(rt * 64) * 1024 + ct * 64;
  int t = threadIdx.x;
#pragma unroll
  for (int p = 0; p < 4; p++) {
    int c = t + p * 256;
    int row = c >> 4, c4 = c & 15;
    float4 v = *(const float4*)(s + (long)row * 1024 + c4 * 4);
    bf16x4 h;
    h[0] = (__bf16)v.x; h[1] = (__bf16)v.y; h[2] = (__bf16)v.z; h[3] = (__bf16)v.w;
    *(bf16x4*)&tile[row][c4 * 4] = h;
  }
  __syncthreads();
#pragma unroll
  for (int p = 0; p < 4; p++) {
    int c = t + p * 256;
    int hr = c >> 4, s4 = c & 15;
    bf16x4 h;
    h[0] = tile[s4 * 4 + 0][hr];
    h[1] = tile[s4 * 4 + 1][hr];
    h[2] = tile[s4 * 4 + 2][hr];
    h[3] = tile[s4 * 4 + 3][hr];
    *(bf16x4*)(dstT + (long)(ct * 64 + hr) * 1024 + rt * 64 + s4 * 4) = h;
  }
}

// ---------------------------------------------------------------------------
// qgemm: Q = Obf @ Wt. 128x128 tile, BK=32, XCD/L2 remap (grid 2560),
// 3-buffer counted-vmcnt pipeline + XOR swizzle (both sides) + setprio.
__global__ __launch_bounds__(256, 3) void qgemm_b16(
    const __bf16* __restrict__ A, const __bf16* __restrict__ Bt, __bf16* __restrict__ C)
{
  __shared__ __align__(16) char ldsb[3 * 16384];  // 48 KB: per buf A[8K] B[8K]
  int lin = blockIdx.x;
  int xcd = lin & 7, idx = lin >> 3;
  int rt = xcd * 40 + (idx >> 3), ct = idx & 7;
  int t = threadIdx.x, l = t & 63, w = t >> 6;
  int wm = w >> 1, wn = w & 1;
  f32x4 acc[4][4] = {};

  const char *gA0, *gA1, *gB0, *gB1;
  {
    int c0 = t, c1 = t + 256;
    int r0 = c0 >> 2, h0 = (c0 & 3) ^ ((c0 >> 3) & 3);
    int r1 = c1 >> 2, h1 = (c1 & 3) ^ ((c1 >> 3) & 3);
    gA0 = (const char*)(A + (long)(rt * 128 + r0) * 1024 + h0 * 8);
    gA1 = (const char*)(A + (long)(rt * 128 + r1) * 1024 + h1 * 8);
    gB0 = (const char*)(Bt + (long)(ct * 128 + r0) * 1024 + h0 * 8);
    gB1 = (const char*)(Bt + (long)(ct * 128 + r1) * 1024 + h1 * 8);
  }
  int dst0 = w * 1024, dst1 = (w + 4) * 1024;

#define STAGE(BUF)                                                \
  {                                                               \
    char* base = ldsb + (BUF) * 16384;                            \
    gload_lds16(gA0, base + dst0); gA0 += 64;                     \
    gload_lds16(gA1, base + dst1); gA1 += 64;                     \
    gload_lds16(gB0, base + 8192 + dst0); gB0 += 64;              \
    gload_lds16(gB1, base + 8192 + dst1); gB1 += 64;              \
  }

  int lr = l & 15, sl = l >> 4;
  int swz = (sl ^ ((lr >> 1) & 3)) * 16;
  int aoff = (wm * 64 + lr) * 64 + swz;
  int boff = 8192 + (wn * 64 + lr) * 64 + swz;

#define COMPUTE(BUF)                                                                   \
  {                                                                                    \
    const char* base = ldsb + (BUF) * 16384;                                           \
    bf16x8 af[4], bfr[4];                                                              \
    _Pragma("unroll") for (int i = 0; i < 4; i++) {                                    \
      af[i]  = *(const bf16x8*)(base + aoff + i * 1024);                               \
      bfr[i] = *(const bf16x8*)(base + boff + i * 1024);                               \
    }                                                                                  \
    __builtin_amdgcn_s_setprio(1);                                                     \
    _Pragma("unroll") for (int i = 0; i < 4; i++)                                      \
      _Pragma("unroll") for (int j = 0; j < 4; j++)                                    \
        acc[i][j] = __builtin_amdgcn_mfma_f32_16x16x32_bf16(af[i], bfr[j],             \
                                                            acc[i][j], 0, 0, 0);       \
    __builtin_amdgcn_s_setprio(0);                                                     \
  }

#define STEP(CUR, STG)                                          \
  asm volatile("s_waitcnt vmcnt(4)" ::: "memory");              \
  __builtin_amdgcn_s_barrier();                                 \
  STAGE(STG);                                                   \
  COMPUTE(CUR);

  STAGE(0)
  STAGE(1)
  for (int it = 0; it < 10; it++) {
    STEP(0, 2)
    STEP(1, 0)
    STEP(2, 1)
  }
  asm volatile("s_waitcnt vmcnt(4)" ::: "memory");
  __builtin_amdgcn_s_barrier();
  COMPUTE(0)
  asm volatile("s_waitcnt vmcnt(0)" ::: "memory");
  __builtin_amdgcn_s_barrier();
  COMPUTE(1)
#undef STEP
#undef COMPUTE
#undef STAGE

#pragma unroll
  for (int i = 0; i < 4; i++) {
    long mrow = (long)rt * 128 + wm * 64 + i * 16 + ((l >> 4) << 2);
#pragma unroll
    for (int j = 0; j < 4; j++) {
      int n = ct * 128 + wn * 64 + j * 16 + (l & 15);
#pragma unroll
      for (int r = 0; r < 4; r++)
        C[(mrow + r) * 1024 + n] = (__bf16)acc[i][j][r];
    }
  }
}

// ---------------------------------------------------------------------------
// gram: 20 cross-grams + lane-local softmax -> V.
// Round 9: register fragment double-buffer. Per step t:
//   vmcnt(5) [stage(t+1) done, stage(t+2) in flight] -> s_barrier ->
//   STAGE(t+3) -> LOADF frags(t+1) -> MFMA on frags(t) -> lgkmcnt(0).
__global__ __launch_bounds__(256, 2) void gram_b16(
    const __bf16* __restrict__ Q, const __bf16* __restrict__ O, __bf16* __restrict__ V)
{
  __shared__ __align__(16) char ldsb[3 * 20480];  // 60 KB
  int bid = blockIdx.x;
  int xcd = bid & 7, idx = bid >> 3;          // 2048 = 8 XCD x 256 (bijective)
  int b = xcd * 4 + (idx >> 6);               // 4 batches per XCD
  int rem = idx & 63;
  int s1t = rem >> 3, s2t = rem & 7;          // s1t-major within batch
  int t = threadIdx.x, l = t & 63, w = t >> 6;
  int pr = w >> 1, pc = w & 1;
  f32x4 acc[20] = {};

  long qrow0 = (long)b * SS + s1t * 32;
  long orow0 = (long)b * SS + s2t * 32;
  int slog = (l & 3) ^ ((l >> 3) & 3);
  const char* gp0; const char* gp1; const char* gp2; const char* gp3; const char* gp4;
#define GP_INIT(GP, P)                                                                \
  {                                                                                   \
    int g = 4 * (P) + w;                                                              \
    int isQ = g < 10;                                                                 \
    int gg = isQ ? g : g - 10;                                                        \
    long row = (long)(gg >> 1) * (BB * SS) + (isQ ? qrow0 : orow0) + (g & 1) * 16 +   \
               (l >> 2);                                                              \
    GP = (const char*)((isQ ? Q : O) + row * HH + slog * 8);                          \
  }
  GP_INIT(gp0, 0) GP_INIT(gp1, 1) GP_INIT(gp2, 2) GP_INIT(gp3, 3) GP_INIT(gp4, 4)
#undef GP_INIT
  int g0 = w, g1 = 4 + w, g2 = 8 + w, g3 = 12 + w, g4 = 16 + w;

#define STAGE(BUF)                                                      \
  {                                                                     \
    char* base = ldsb + (BUF) * 20480;                                  \
    gload_lds16(gp0, base + g0 * 1024); gp0 += 64;                      \
    gload_lds16(gp1, base + g1 * 1024); gp1 += 64;                      \
    gload_lds16(gp2, base + g2 * 1024); gp2 += 64;                      \
    gload_lds16(gp3, base + g3 * 1024); gp3 += 64;                      \
    gload_lds16(gp4, base + g4 * 1024); gp4 += 64;                      \
  }

  int lr = l & 15, sl = l >> 4;
  int swz = (sl ^ ((lr >> 1) & 3)) * 16;
  int qoff = (pr * 16 + lr) * 64 + swz;
  int ooff = 10240 + (pc * 16 + lr) * 64 + swz;

  bf16x8 qE[5], oE[5], qO[5], oO[5];  // two fragment sets (even/odd steps)

#define LOADF(QF, OF, BUF)                                                    \
  {                                                                           \
    const char* base = ldsb + (BUF) * 20480;                                  \
    _Pragma("unroll") for (int m = 0; m < 5; m++) {                           \
      QF[m] = *(const bf16x8*)(base + m * 2048 + qoff);                       \
      OF[m] = *(const bf16x8*)(base + m * 2048 + ooff);                       \
    }                                                                         \
  }

#define MFMA20(QF, OF)                                                                 \
  {                                                                                    \
    __builtin_amdgcn_s_setprio(1);                                                     \
    _Pragma("unroll") for (int i = 0; i < 5; i++) {                                    \
      _Pragma("unroll") for (int n = 0; n < 5; n++) {                                  \
        if (n != i)                                                                    \
          acc[PAIR(i, n)] =                                                            \
              __builtin_amdgcn_mfma_f32_16x16x32_bf16(QF[i], OF[n], acc[PAIR(i, n)],   \
                                                      0, 0, 0);                        \
      }                                                                                \
    }                                                                                  \
    __builtin_amdgcn_s_setprio(0);                                                     \
  }

#define VMC5  asm volatile("s_waitcnt vmcnt(5)" ::: "memory")
#define VMC0  asm volatile("s_waitcnt vmcnt(0)" ::: "memory")
#define LGK0  asm volatile("s_waitcnt lgkmcnt(0)" ::: "memory")

  // prologue: stage 0,1,2 ; prefetch frags(0) from buf0
  STAGE(0)
  STAGE(1)
  STAGE(2)
  asm volatile("s_waitcnt vmcnt(10)" ::: "memory");  // stage(0) done (own)
  __builtin_amdgcn_s_barrier();                      // stage(0) done (all waves)
  LOADF(qE, oE, 0)
  LGK0;

  int bS = 0, bL = 1;  // stage(t+3) -> buf[(t+3)%3]; LOADF(t+1) -> buf[(t+1)%3]
  for (int it = 0; it < 14; it++) {  // steps t = 0..27
    // even step
    VMC5;
    __builtin_amdgcn_s_barrier();
    STAGE(bS); bS = bS == 2 ? 0 : bS + 1;
    LOADF(qO, oO, bL) bL = bL == 2 ? 0 : bL + 1;
    MFMA20(qE, oE)
    LGK0;
    // odd step
    VMC5;
    __builtin_amdgcn_s_barrier();
    STAGE(bS); bS = bS == 2 ? 0 : bS + 1;
    LOADF(qE, oE, bL) bL = bL == 2 ? 0 : bL + 1;
    MFMA20(qO, oO)
    LGK0;
  }
  // t = 28: stage(31), prefetch frags(29)
  VMC5;
  __builtin_amdgcn_s_barrier();
  STAGE(bS);
  LOADF(qO, oO, bL) bL = bL == 2 ? 0 : bL + 1;
  MFMA20(qE, oE)
  LGK0;
  // t = 29: prefetch frags(30)
  VMC5;
  __builtin_amdgcn_s_barrier();
  LOADF(qE, oE, bL) bL = bL == 2 ? 0 : bL + 1;
  MFMA20(qO, oO)
  LGK0;
  // t = 30: drain, prefetch frags(31)
  VMC0;
  __builtin_amdgcn_s_barrier();
  LOADF(qO, oO, bL)
  MFMA20(qE, oE)
  LGK0;
  // t = 31
  MFMA20(qO, oO)
#undef VMC5
#undef VMC0
#undef LGK0
#undef MFMA20
#undef LOADF
#undef STAGE

  int s1g = s1t * 32 + pr * 16 + ((l >> 4) << 2);
  int s2g = s2t * 32 + pc * 16 + (l & 15);
#pragma unroll
  for (int r = 0; r < 4; r++) {
    float vacc[5] = {0.f, 0.f, 0.f, 0.f, 0.f};
#pragma unroll
    for (int i = 0; i < 5; i++) {
      float gg[5];
      float mx = -3.0e38f;
#pragma unroll
      for (int n = 0; n < 5; n++)
        if (n != i) { gg[n] = acc[PAIR(i, n)][r]; mx = fmaxf(mx, gg[n]); }
      float ee[5], ssum = 0.f;
#pragma unroll
      for (int n = 0; n < 5; n++)
        if (n != i) { ee[n] = __expf(gg[n] - mx); ssum += ee[n]; }
      float inv = 1.0f / ssum;
#pragma unroll
      for (int n = 0; n < 5; n++)
        if (n != i) vacc[n] += ee[n] * inv;
    }
#pragma unroll
    for (int n = 0; n < 5; n++)
      V[((long)(n * 32 + b) * 256 + s1g + r) * 256 + s2g] = (__bf16)vacc[n];
  }
}

// ---------------------------------------------------------------------------
// out = 0.5 * sum_n V_n @ o_n (per batch). A: V rows (bf16, s2-contig).
// B: Obf bf16 (s2 x h), transposed in LDS via 4x4 register sub-blocks.
__global__ __launch_bounds__(256) void pvgemm(
    const __bf16* __restrict__ Vb, const __bf16* __restrict__ Obf, float* __restrict__ out)
{
  __shared__ __bf16 smA[128][40];
  __shared__ __bf16 smB[128][40];
  int bid = blockIdx.x;
  int b = bid >> 4, s1t = (bid >> 3) & 1, ht = bid & 7;
  int t = threadIdx.x, l = t & 63, w = t >> 6;
  int wm = w >> 1, wn = w & 1;
  f32x4 acc[4][4] = {};
#pragma unroll
  for (int n = 0; n < 5; n++) {
    const __bf16* On = Obf + (long)n * BB * SS * HH;
    for (int st2 = 0; st2 < 8; st2++) {
      int s20 = st2 * 32;
#pragma unroll
      for (int p = 0; p < 2; p++) {
        int c = t + p * 256;
        int row = c >> 2, sl = c & 3;
        *(bf16x8*)&smA[row][sl * 8] =
            *(const bf16x8*)(Vb + (long)(n * BB + b) * SS * SS + (long)(s1t * 128 + row) * SS +
                             s20 + sl * 8);
      }
      {
        int h4 = (t & 31) * 4, s2q = (t >> 5) * 4;
        const __bf16* src = On + ((long)b * 256 + s20 + s2q) * 1024 + ht * 128 + h4;
        bf16x4 v0 = *(const bf16x4*)(src);
        bf16x4 v1 = *(const bf16x4*)(src + 1024);
        bf16x4 v2 = *(const bf16x4*)(src + 2048);
        bf16x4 v3 = *(const bf16x4*)(src + 3072);
        bf16x4 c0, c1, c2, c3;
        c0[0] = v0[0]; c0[1] = v1[0]; c0[2] = v2[0]; c0[3] = v3[0];
        c1[0] = v0[1]; c1[1] = v1[1]; c1[2] = v2[1]; c1[3] = v3[1];
        c2[0] = v0[2]; c2[1] = v1[2]; c2[2] = v2[2]; c2[3] = v3[2];
        c3[0] = v0[3]; c3[1] = v1[3]; c3[2] = v2[3]; c3[3] = v3[3];
        *(bf16x4*)&smB[h4 + 0][s2q] = c0;
        *(bf16x4*)&smB[h4 + 1][s2q] = c1;
        *(bf16x4*)&smB[h4 + 2][s2q] = c2;
        *(bf16x4*)&smB[h4 + 3][s2q] = c3;
      }
      __syncthreads();
      bf16x8 af[4], bfr[4];
      int sl = l >> 4, lr = l & 15;
#pragma unroll
      for (int i = 0; i < 4; i++) {
        af[i]  = *(const bf16x8*)&smA[wm * 64 + i * 16 + lr][sl * 8];
        bfr[i] = *(const bf16x8*)&smB[wn * 64 + i * 16 + lr][sl * 8];
      }
#pragma unroll
      for (int i = 0; i < 4; i++)
#pragma unroll
        for (int j = 0; j < 4; j++)
          acc[i][j] = __builtin_amdgcn_mfma_f32_16x16x32_bf16(af[i], bfr[j], acc[i][j], 0, 0, 0);
      __syncthreads();
    }
  }
#pragma unroll
  for (int i = 0; i < 4; i++) {
    int m = s1t * 128 + wm * 64 + i * 16 + ((l >> 4) << 2);
#pragma unroll
    for (int j = 0; j < 4; j++) {
      int n = ht * 128 + wn * 64 + j * 16 + (l & 15);
#pragma unroll
      for (int r = 0; r < 4; r++)
        out[(long)(b * SS + m + r) * HH + n] = 0.5f * acc[i][j][r];
    }
  }
}

// ---------------------------------------------------------------------------
extern "C" void kernel_launch(void* const* d_in, const int* in_sizes, int n_in,
                              void* d_out, int out_size, void* d_ws, size_t ws_size,
                              hipStream_t stream)
{
  const size_t SZ_W = (size_t)HH * HH * 2;           //  2 MB
  const size_t SZ_Q = (size_t)5 * BB * SS * HH * 2;  // 84 MB
  const size_t SZ_V = (size_t)5 * BB * SS * SS * 2;  // 21 MB
  const size_t SZ_O = (size_t)5 * BB * SS * HH * 2;  // 84 MB
  const size_t NEED = SZ_W + SZ_Q + SZ_V + SZ_O;     // 191 MB (proven available r4)
  if (ws_size < NEED) {
    canary<<<1, 1, 0, stream>>>((float*)d_out, (float)(ws_size >> 20));
    return;
  }
  char* ws = (char*)d_ws;
  __bf16* Wt  = (__bf16*)ws;
  __bf16* Qb  = (__bf16*)(ws + SZ_W);
  __bf16* Vb  = (__bf16*)(ws + SZ_W + SZ_Q);
  __bf16* Obf = (__bf16*)(ws + SZ_W + SZ_Q + SZ_V);
  const float* o0 = (const float*)d_in[0];
  const float* o1 = (const float*)d_in[1];
  const float* o2 = (const float*)d_in[2];
  const float* o3 = (const float*)d_in[3];
  const float* o4 = (const float*)d_in[4];

  cast_trW<<<256, 256, 0, stream>>>((const float*)d_in[5], Wt);
  cast_all<<<5 * 4096, 256, 0, stream>>>(o0, o1, o2, o3, o4, Obf);
  qgemm_b16<<<2560, 256, 0, stream>>>(Obf, Wt, Qb);
  gram_b16<<<2048, 256, 0, stream>>>(Qb, Obf, Vb);
  pvgemm<<<512, 256, 0, stream>>>(Vb, Obf, (float*)d_out);
}